// Round 7
// baseline (264.379 us; speedup 1.0000x reference)
//
#include <hip/hip_runtime.h>
#include <hip/hip_bf16.h>

#define N_NODES 50000
#define N_EDGES 600000
#define F 128

#define GEMM_BLOCKS 782   // ceil(50000/64)
#define EDGE_BLOCKS 2344  // ceil(600000/256)

typedef unsigned short bf16_t;
typedef __attribute__((ext_vector_type(8))) short short8v;
typedef __attribute__((ext_vector_type(8))) unsigned short ushort8v;
typedef __attribute__((ext_vector_type(4))) float f32x4;

__device__ inline float bf2f(bf16_t u) {
    union { unsigned int i; float f; } c;
    c.i = ((unsigned int)u) << 16;
    return c.f;
}
__device__ inline bf16_t f2bf(float f) {  // round-to-nearest-even
    union { float f; unsigned int i; } c;
    c.f = f;
    unsigned int lsb = (c.i >> 16) & 1;
    c.i += 0x7fffu + lsb;
    return (bf16_t)(c.i >> 16);
}

// ---------------------------------------------------------------------------
// Wc = w2 @ w1 (plain [p][j]), bc = w2@b1 + b2.  Also zeroes cnt[].
// ---------------------------------------------------------------------------
__global__ void k_fuse(const float* __restrict__ w1, const float* __restrict__ b1,
                       const float* __restrict__ w2, const float* __restrict__ b2,
                       float* __restrict__ Wc, float* __restrict__ bc,
                       int* __restrict__ cnt) {
    int p = blockIdx.x;
    int j = threadIdx.x;
    int gid = p * 128 + j;
    for (int i = gid; i < N_NODES; i += 128 * 128) cnt[i] = 0;

    float s = 0.f;
    for (int o = 0; o < F; ++o) s = fmaf(w2[p * F + o], w1[o * F + j], s);
    Wc[p * F + j] = s;
    if (j == 0) {
        float t = b2[p];
        for (int o = 0; o < F; ++o) t = fmaf(w2[p * F + o], b1[o], t);
        bc[p] = t;
    }
}

// ---------------------------------------------------------------------------
// Heterogeneous: blocks [0,128) compute Mbf[p][k] = (W^T W^T)[k][p] (bf16,
// B-operand layout) and v1 = Wc*bc; blocks [128, 128+EDGE_BLOCKS) run the
// degree histogram (cnt[dst]++). Independent roles overlap on device.
// ---------------------------------------------------------------------------
__global__ __launch_bounds__(256)
void k_fuse2h(const float* __restrict__ Wc, const float* __restrict__ bc,
              bf16_t* __restrict__ Mbf, float* __restrict__ v1,
              const int* __restrict__ dst, int* __restrict__ cnt) {
    int bid = blockIdx.x;
    int tid = threadIdx.x;
    if (bid < 128) {
        if (tid < 128) {
            int k = bid, p = tid;
            float s = 0.f;
            for (int o = 0; o < F; ++o) s = fmaf(Wc[p * F + o], Wc[o * F + k], s);
            Mbf[p * F + k] = f2bf(s);
            if (k == 0) {
                float t = 0.f;
                for (int o = 0; o < F; ++o) t = fmaf(Wc[p * F + o], bc[o], t);
                v1[p] = t;
            }
        }
        return;
    }
    int e = (bid - 128) * 256 + tid;
    if (e < N_EDGES) atomicAdd(&cnt[dst[e]], 1);
}

// ---------------------------------------------------------------------------
// Single-block exclusive scan of cnt[0..N) -> rofs[0..N] (rofs[N]=E), plus a
// writable copy wofs for the scatter pass. 1024 threads, 49 elems each.
// ---------------------------------------------------------------------------
__global__ __launch_bounds__(1024)
void k_scan(const int* __restrict__ cnt, int* __restrict__ rofs,
            int* __restrict__ wofs) {
    __shared__ int part[1024];
    const int t = threadIdx.x;
    const int CH = 49;  // 1024*49 = 50176 >= 50001
    const int base = t * CH;

    int s = 0;
    for (int i = 0; i < CH; ++i) {
        int idx = base + i;
        if (idx < N_NODES) s += cnt[idx];
    }
    part[t] = s;
    __syncthreads();
    for (int off = 1; off < 1024; off <<= 1) {
        int v = (t >= off) ? part[t - off] : 0;
        __syncthreads();
        part[t] += v;
        __syncthreads();
    }
    int run = (t == 0) ? 0 : part[t - 1];
    for (int i = 0; i < CH; ++i) {
        int idx = base + i;
        if (idx < N_NODES) {
            rofs[idx] = run;
            wofs[idx] = run;
            run += cnt[idx];
        } else if (idx == N_NODES) {
            rofs[idx] = run;  // == N_EDGES
        }
    }
}

// ---------------------------------------------------------------------------
// Heterogeneous: blocks [0, GEMM_BLOCKS) = MFMA GEMM g = x*M; blocks
// [GEMM_BLOCKS, +EDGE_BLOCKS) = CSR scatter csr[wofs[d]++] = src (dense
// 1.2MB target -> L2/L3-resident lines, no per-edge HBM write-allocate).
// ---------------------------------------------------------------------------
__global__ __launch_bounds__(256, 4)
void k_main(const float* __restrict__ X, const bf16_t* __restrict__ Mbf,
            bf16_t* __restrict__ G,
            const int* __restrict__ src, const int* __restrict__ dst,
            int* __restrict__ wofs, unsigned short* __restrict__ csr) {
    const int bid = blockIdx.x;
    const int tid = threadIdx.x;

    if (bid >= GEMM_BLOCKS) {
        int e = (bid - GEMM_BLOCKS) * 256 + tid;
        if (e < N_EDGES) {
            int d = dst[e];
            int pos = atomicAdd(&wofs[d], 1);
            csr[pos] = (unsigned short)src[e];
        }
        return;
    }

    // ---- GEMM role ----
    __shared__ unsigned short Xs[64 * 128];  // bf16, swizzled
    const int row0 = bid * 64;

    for (int idx = tid; idx < 1024; idx += 256) {
        int r = idx >> 4, c = idx & 15;
        int grow = row0 + r;
        float4 va = {0.f, 0.f, 0.f, 0.f}, vb = {0.f, 0.f, 0.f, 0.f};
        if (grow < N_NODES) {
            const float4* xr = (const float4*)(X + (size_t)grow * F);
            va = xr[2 * c];
            vb = xr[2 * c + 1];
        }
        ushort8v u;
        u[0] = f2bf(va.x); u[1] = f2bf(va.y); u[2] = f2bf(va.z); u[3] = f2bf(va.w);
        u[4] = f2bf(vb.x); u[5] = f2bf(vb.y); u[6] = f2bf(vb.z); u[7] = f2bf(vb.w);
        *(ushort8v*)&Xs[r * 128 + (((c ^ (r & 7)) << 3))] = u;
    }
    __syncthreads();

    const int wid = tid >> 6;
    const int lane = tid & 63;
    const int wr = wid >> 1;
    const int wc = wid & 1;
    const int l15 = lane & 15;
    const int l4 = lane >> 4;
    const int sw = (l15 & 7);

    f32x4 acc[2][4] = {};

#pragma unroll
    for (int kc = 0; kc < 4; ++kc) {
        const int cS = ((kc * 4 + l4) ^ sw) << 3;
        short8v a0 = *(const short8v*)&Xs[(wr * 32 + 0 * 16 + l15) * 128 + cS];
        short8v a1 = *(const short8v*)&Xs[(wr * 32 + 1 * 16 + l15) * 128 + cS];
        const bf16_t* mb = Mbf + (size_t)(wc * 64 + l15) * F + kc * 32 + 8 * l4;
        short8v b0 = *(const short8v*)(mb + 0 * 16 * F);
        short8v b1 = *(const short8v*)(mb + 1 * 16 * F);
        short8v b2 = *(const short8v*)(mb + 2 * 16 * F);
        short8v b3 = *(const short8v*)(mb + 3 * 16 * F);
        acc[0][0] = __builtin_amdgcn_mfma_f32_16x16x32_bf16(a0, b0, acc[0][0], 0, 0, 0);
        acc[0][1] = __builtin_amdgcn_mfma_f32_16x16x32_bf16(a0, b1, acc[0][1], 0, 0, 0);
        acc[0][2] = __builtin_amdgcn_mfma_f32_16x16x32_bf16(a0, b2, acc[0][2], 0, 0, 0);
        acc[0][3] = __builtin_amdgcn_mfma_f32_16x16x32_bf16(a0, b3, acc[0][3], 0, 0, 0);
        acc[1][0] = __builtin_amdgcn_mfma_f32_16x16x32_bf16(a1, b0, acc[1][0], 0, 0, 0);
        acc[1][1] = __builtin_amdgcn_mfma_f32_16x16x32_bf16(a1, b1, acc[1][1], 0, 0, 0);
        acc[1][2] = __builtin_amdgcn_mfma_f32_16x16x32_bf16(a1, b2, acc[1][2], 0, 0, 0);
        acc[1][3] = __builtin_amdgcn_mfma_f32_16x16x32_bf16(a1, b3, acc[1][3], 0, 0, 0);
    }

#pragma unroll
    for (int mt = 0; mt < 2; ++mt) {
#pragma unroll
        for (int nt = 0; nt < 4; ++nt) {
#pragma unroll
            for (int r = 0; r < 4; ++r) {
                int grow = row0 + wr * 32 + mt * 16 + l4 * 4 + r;
                if (grow < N_NODES) {
                    int gcol = wc * 64 + nt * 16 + l15;
                    G[(size_t)grow * F + gcol] = f2bf(acc[mt][nt][r]);
                }
            }
        }
    }
}

// ---------------------------------------------------------------------------
// O[n] = H[n] + sum_{s in csr[rofs[n]..rofs[n+1])} H[s].  Quarter-wave
// (16 lanes x ushort8 = 256B row); 4 independent gather chains per wave.
// ---------------------------------------------------------------------------
__global__ __launch_bounds__(256)
void k_agg(const bf16_t* __restrict__ H, const int* __restrict__ rofs,
           const unsigned short* __restrict__ csr, bf16_t* __restrict__ O,
           int n_rows) {
    int tid = threadIdx.x;
    int lane = tid & 15;
    int node = blockIdx.x * 16 + (tid >> 4);
    if (node >= n_rows) return;

    int r0 = rofs[node];
    int deg = rofs[node + 1] - r0;

    ushort8v u = ((const ushort8v*)(H + (size_t)node * F))[lane];
    float a0 = bf2f(u[0]), a1 = bf2f(u[1]), a2 = bf2f(u[2]), a3 = bf2f(u[3]);
    float a4 = bf2f(u[4]), a5 = bf2f(u[5]), a6 = bf2f(u[6]), a7 = bf2f(u[7]);

    const unsigned short* bk = csr + r0;
    int i = 0;
    for (; i + 4 <= deg; i += 4) {
        int s0 = bk[i + 0], s1 = bk[i + 1], s2 = bk[i + 2], s3 = bk[i + 3];
        ushort8v u0 = ((const ushort8v*)(H + (size_t)s0 * F))[lane];
        ushort8v u1 = ((const ushort8v*)(H + (size_t)s1 * F))[lane];
        ushort8v u2 = ((const ushort8v*)(H + (size_t)s2 * F))[lane];
        ushort8v u3 = ((const ushort8v*)(H + (size_t)s3 * F))[lane];
        a0 += bf2f(u0[0]) + bf2f(u1[0]) + bf2f(u2[0]) + bf2f(u3[0]);
        a1 += bf2f(u0[1]) + bf2f(u1[1]) + bf2f(u2[1]) + bf2f(u3[1]);
        a2 += bf2f(u0[2]) + bf2f(u1[2]) + bf2f(u2[2]) + bf2f(u3[2]);
        a3 += bf2f(u0[3]) + bf2f(u1[3]) + bf2f(u2[3]) + bf2f(u3[3]);
        a4 += bf2f(u0[4]) + bf2f(u1[4]) + bf2f(u2[4]) + bf2f(u3[4]);
        a5 += bf2f(u0[5]) + bf2f(u1[5]) + bf2f(u2[5]) + bf2f(u3[5]);
        a6 += bf2f(u0[6]) + bf2f(u1[6]) + bf2f(u2[6]) + bf2f(u3[6]);
        a7 += bf2f(u0[7]) + bf2f(u1[7]) + bf2f(u2[7]) + bf2f(u3[7]);
    }
    for (; i < deg; ++i) {
        ushort8v uv = ((const ushort8v*)(H + (size_t)bk[i] * F))[lane];
        a0 += bf2f(uv[0]); a1 += bf2f(uv[1]); a2 += bf2f(uv[2]); a3 += bf2f(uv[3]);
        a4 += bf2f(uv[4]); a5 += bf2f(uv[5]); a6 += bf2f(uv[6]); a7 += bf2f(uv[7]);
    }
    ushort8v o;
    o[0] = f2bf(a0); o[1] = f2bf(a1); o[2] = f2bf(a2); o[3] = f2bf(a3);
    o[4] = f2bf(a4); o[5] = f2bf(a5); o[6] = f2bf(a6); o[7] = f2bf(a7);
    ((ushort8v*)(O + (size_t)node * F))[lane] = o;
}

// ---------------------------------------------------------------------------
// out[n] = log_softmax( (S*H)[n] + sd_n*v1 + d_n*bc ), sd inline via cnt
// gathers; softmax reduced over the 16-lane group (xor offsets <= 8).
// ---------------------------------------------------------------------------
__global__ __launch_bounds__(256)
void k_agg_ep(const bf16_t* __restrict__ H, const int* __restrict__ rofs,
              const unsigned short* __restrict__ csr, const int* __restrict__ cnt,
              const float* __restrict__ v1, const float* __restrict__ bc,
              float* __restrict__ O, int n_rows) {
    int tid = threadIdx.x;
    int lane = tid & 15;
    int node = blockIdx.x * 16 + (tid >> 4);
    if (node >= n_rows) return;

    int r0 = rofs[node];
    int deg = rofs[node + 1] - r0;

    ushort8v u = ((const ushort8v*)(H + (size_t)node * F))[lane];
    float a0 = bf2f(u[0]), a1 = bf2f(u[1]), a2 = bf2f(u[2]), a3 = bf2f(u[3]);
    float a4 = bf2f(u[4]), a5 = bf2f(u[5]), a6 = bf2f(u[6]), a7 = bf2f(u[7]);

    const unsigned short* bk = csr + r0;

    int sdi = (lane == 0) ? (deg + 1) : 0;
    for (int j = lane; j < deg; j += 16) sdi += cnt[bk[j]] + 1;

    int i = 0;
    for (; i + 4 <= deg; i += 4) {
        int s0 = bk[i + 0], s1 = bk[i + 1], s2 = bk[i + 2], s3 = bk[i + 3];
        ushort8v u0 = ((const ushort8v*)(H + (size_t)s0 * F))[lane];
        ushort8v u1 = ((const ushort8v*)(H + (size_t)s1 * F))[lane];
        ushort8v u2 = ((const ushort8v*)(H + (size_t)s2 * F))[lane];
        ushort8v u3 = ((const ushort8v*)(H + (size_t)s3 * F))[lane];
        a0 += bf2f(u0[0]) + bf2f(u1[0]) + bf2f(u2[0]) + bf2f(u3[0]);
        a1 += bf2f(u0[1]) + bf2f(u1[1]) + bf2f(u2[1]) + bf2f(u3[1]);
        a2 += bf2f(u0[2]) + bf2f(u1[2]) + bf2f(u2[2]) + bf2f(u3[2]);
        a3 += bf2f(u0[3]) + bf2f(u1[3]) + bf2f(u2[3]) + bf2f(u3[3]);
        a4 += bf2f(u0[4]) + bf2f(u1[4]) + bf2f(u2[4]) + bf2f(u3[4]);
        a5 += bf2f(u0[5]) + bf2f(u1[5]) + bf2f(u2[5]) + bf2f(u3[5]);
        a6 += bf2f(u0[6]) + bf2f(u1[6]) + bf2f(u2[6]) + bf2f(u3[6]);
        a7 += bf2f(u0[7]) + bf2f(u1[7]) + bf2f(u2[7]) + bf2f(u3[7]);
    }
    for (; i < deg; ++i) {
        ushort8v uv = ((const ushort8v*)(H + (size_t)bk[i] * F))[lane];
        a0 += bf2f(uv[0]); a1 += bf2f(uv[1]); a2 += bf2f(uv[2]); a3 += bf2f(uv[3]);
        a4 += bf2f(uv[4]); a5 += bf2f(uv[5]); a6 += bf2f(uv[6]); a7 += bf2f(uv[7]);
    }

#pragma unroll
    for (int o = 8; o; o >>= 1) sdi += __shfl_xor(sdi, o);
    float sdn = (float)sdi;
    float dn = (float)(deg + 1);
    float4 v1a = ((const float4*)v1)[2 * lane], v1b = ((const float4*)v1)[2 * lane + 1];
    float4 bca = ((const float4*)bc)[2 * lane], bcb = ((const float4*)bc)[2 * lane + 1];
    a0 += sdn * v1a.x + dn * bca.x;
    a1 += sdn * v1a.y + dn * bca.y;
    a2 += sdn * v1a.z + dn * bca.z;
    a3 += sdn * v1a.w + dn * bca.w;
    a4 += sdn * v1b.x + dn * bcb.x;
    a5 += sdn * v1b.y + dn * bcb.y;
    a6 += sdn * v1b.z + dn * bcb.z;
    a7 += sdn * v1b.w + dn * bcb.w;

    float m = fmaxf(fmaxf(fmaxf(a0, a1), fmaxf(a2, a3)),
                    fmaxf(fmaxf(a4, a5), fmaxf(a6, a7)));
#pragma unroll
    for (int o = 8; o; o >>= 1) m = fmaxf(m, __shfl_xor(m, o));
    float s = expf(a0 - m) + expf(a1 - m) + expf(a2 - m) + expf(a3 - m)
            + expf(a4 - m) + expf(a5 - m) + expf(a6 - m) + expf(a7 - m);
#pragma unroll
    for (int o = 8; o; o >>= 1) s += __shfl_xor(s, o);
    float lse = m + logf(s);
    float4 oa, ob;
    oa.x = a0 - lse; oa.y = a1 - lse; oa.z = a2 - lse; oa.w = a3 - lse;
    ob.x = a4 - lse; ob.y = a5 - lse; ob.z = a6 - lse; ob.w = a7 - lse;
    ((float4*)(O + (size_t)node * F))[2 * lane] = oa;
    ((float4*)(O + (size_t)node * F))[2 * lane + 1] = ob;
}

extern "C" void kernel_launch(void* const* d_in, const int* in_sizes, int n_in,
                              void* d_out, int out_size, void* d_ws, size_t ws_size,
                              hipStream_t stream) {
    const float* x  = (const float*)d_in[0];
    const int* ei   = (const int*)d_in[1];
    const float* w1 = (const float*)d_in[2];
    const float* b1 = (const float*)d_in[3];
    const float* w2 = (const float*)d_in[4];
    const float* b2 = (const float*)d_in[5];
    float* out = (float*)d_out;

    const int* src = ei;
    const int* dst = ei + N_EDGES;

    // workspace layout (float offsets, 16B aligned)
    float* ws       = (float*)d_ws;
    float* Wc       = ws;                          // 16384
    float* bc       = ws + 16384;                  // 128
    float* v1       = ws + 16512;                  // 128
    bf16_t* Mbf     = (bf16_t*)(ws + 16640);       // 16384 bf16 (8192 f)
    int*   cnt      = (int*)(ws + 24832);          // 50048
    int*   rofs     = (int*)(ws + 74880);          // 50001 (pad 50048)
    int*   wofs     = (int*)(ws + 124928);         // 50048
    unsigned short* csr = (unsigned short*)(ws + 174976);  // 600000 u16 (300000 f)
    bf16_t* g       = (bf16_t*)(ws + 474976);      // 6.4M bf16 (3.2M f)
    bf16_t* a1      = (bf16_t*)(ws + 3674976);     // 6.4M bf16

    const int node_grid = (N_NODES + 15) / 16;  // 3125

    k_fuse<<<128, 128, 0, stream>>>(w1, b1, w2, b2, Wc, bc, cnt);
    // Mbf/v1 || degree histogram
    k_fuse2h<<<128 + EDGE_BLOCKS, 256, 0, stream>>>(Wc, bc, Mbf, v1, dst, cnt);
    k_scan<<<1, 1024, 0, stream>>>(cnt, rofs, wofs);
    // g = x*M (MFMA) || CSR scatter
    k_main<<<GEMM_BLOCKS + EDGE_BLOCKS, 256, 0, stream>>>(x, Mbf, g, src, dst,
                                                          wofs, csr);
    // a1 = S * g
    k_agg<<<node_grid, 256, 0, stream>>>(g, rofs, csr, a1, N_NODES);
    // out = log_softmax(S * a1 + sd*v1^T + d*bc^T)
    k_agg_ep<<<node_grid, 256, 0, stream>>>(a1, rofs, csr, cnt, v1, bc, out, N_NODES);
}

// Round 8
// 145.629 us; speedup vs baseline: 1.8154x; 1.8154x over previous
//
#include <hip/hip_runtime.h>
#include <hip/hip_bf16.h>

#define N_NODES 50000
#define N_EDGES 600000
#define F 128

#define GEMM_BLOCKS 782   // ceil(50000/64)
#define EDGE_BLOCKS 2344  // ceil(600000/256)
#define SCAN_BLOCKS 196   // ceil(50000/256)

typedef unsigned short bf16_t;
typedef __attribute__((ext_vector_type(8))) short short8v;
typedef __attribute__((ext_vector_type(8))) unsigned short ushort8v;
typedef __attribute__((ext_vector_type(4))) float f32x4;

__device__ inline float bf2f(bf16_t u) {
    union { unsigned int i; float f; } c;
    c.i = ((unsigned int)u) << 16;
    return c.f;
}
__device__ inline bf16_t f2bf(float f) {  // round-to-nearest-even
    union { float f; unsigned int i; } c;
    c.f = f;
    unsigned int lsb = (c.i >> 16) & 1;
    c.i += 0x7fffu + lsb;
    return (bf16_t)(c.i >> 16);
}

// ---------------------------------------------------------------------------
// Wc = w2 @ w1 (plain [p][j]), bc = w2@b1 + b2.  Also zeroes cnt[].
// ---------------------------------------------------------------------------
__global__ void k_fuse(const float* __restrict__ w1, const float* __restrict__ b1,
                       const float* __restrict__ w2, const float* __restrict__ b2,
                       float* __restrict__ Wc, float* __restrict__ bc,
                       int* __restrict__ cnt) {
    int p = blockIdx.x;
    int j = threadIdx.x;
    int gid = p * 128 + j;
    for (int i = gid; i < N_NODES; i += 128 * 128) cnt[i] = 0;

    float s = 0.f;
    for (int o = 0; o < F; ++o) s = fmaf(w2[p * F + o], w1[o * F + j], s);
    Wc[p * F + j] = s;
    if (j == 0) {
        float t = b2[p];
        for (int o = 0; o < F; ++o) t = fmaf(w2[p * F + o], b1[o], t);
        bc[p] = t;
    }
}

// ---------------------------------------------------------------------------
// Heterogeneous: blocks [0,128) compute Mbf[p][k] = (W^T W^T)[k][p] (bf16,
// B-operand layout) and v1 = Wc*bc; blocks [128, 128+EDGE_BLOCKS) run the
// degree histogram (cnt[dst]++).
// ---------------------------------------------------------------------------
__global__ __launch_bounds__(256)
void k_fuse2h(const float* __restrict__ Wc, const float* __restrict__ bc,
              bf16_t* __restrict__ Mbf, float* __restrict__ v1,
              const int* __restrict__ dst, int* __restrict__ cnt) {
    int bid = blockIdx.x;
    int tid = threadIdx.x;
    if (bid < 128) {
        if (tid < 128) {
            int k = bid, p = tid;
            float s = 0.f;
            for (int o = 0; o < F; ++o) s = fmaf(Wc[p * F + o], Wc[o * F + k], s);
            Mbf[p * F + k] = f2bf(s);
            if (k == 0) {
                float t = 0.f;
                for (int o = 0; o < F; ++o) t = fmaf(Wc[p * F + o], bc[o], t);
                v1[p] = t;
            }
        }
        return;
    }
    int e = (bid - 128) * 256 + tid;
    if (e < N_EDGES) atomicAdd(&cnt[dst[e]], 1);
}

// ---------------------------------------------------------------------------
// Hierarchical scan, phase 1: bsum[b] = sum of cnt[b*256 .. b*256+255].
// ---------------------------------------------------------------------------
__global__ __launch_bounds__(256)
void k_scan1(const int* __restrict__ cnt, int* __restrict__ bsum) {
    __shared__ int wsum[4];
    int t = threadIdx.x;
    int idx = blockIdx.x * 256 + t;
    int v = (idx < N_NODES) ? cnt[idx] : 0;
#pragma unroll
    for (int o = 32; o; o >>= 1) v += __shfl_xor(v, o);
    if ((t & 63) == 0) wsum[t >> 6] = v;
    __syncthreads();
    if (t == 0) bsum[blockIdx.x] = wsum[0] + wsum[1] + wsum[2] + wsum[3];
}

// ---------------------------------------------------------------------------
// Phase 2: single small block — exclusive scan of SCAN_BLOCKS partials.
// ---------------------------------------------------------------------------
__global__ __launch_bounds__(256)
void k_scan2(const int* __restrict__ bsum, int* __restrict__ bofs) {
    __shared__ int wofs_l[4];
    int t = threadIdx.x;
    int lane = t & 63, wv = t >> 6;
    int v = (t < SCAN_BLOCKS) ? bsum[t] : 0;
    int incl = v;
#pragma unroll
    for (int o = 1; o < 64; o <<= 1) {
        int u = __shfl_up(incl, o);
        if (lane >= o) incl += u;
    }
    if (lane == 63) wofs_l[wv] = incl;
    __syncthreads();
    if (t == 0) {
        int r = 0;
        for (int w = 0; w < 4; ++w) { int x = wofs_l[w]; wofs_l[w] = r; r += x; }
    }
    __syncthreads();
    if (t < SCAN_BLOCKS) bofs[t] = incl - v + wofs_l[wv];
}

// ---------------------------------------------------------------------------
// Phase 3: per-block exclusive scan of cnt + bofs[b] -> rofs, wofs.
// ---------------------------------------------------------------------------
__global__ __launch_bounds__(256)
void k_scan3(const int* __restrict__ cnt, const int* __restrict__ bofs,
             int* __restrict__ rofs, int* __restrict__ wofs) {
    __shared__ int wtot[4];
    int t = threadIdx.x;
    int lane = t & 63, wv = t >> 6;
    int idx = blockIdx.x * 256 + t;
    int v = (idx < N_NODES) ? cnt[idx] : 0;
    int incl = v;
#pragma unroll
    for (int o = 1; o < 64; o <<= 1) {
        int u = __shfl_up(incl, o);
        if (lane >= o) incl += u;
    }
    if (lane == 63) wtot[wv] = incl;
    __syncthreads();
    if (t == 0) {
        int r = 0;
        for (int w = 0; w < 4; ++w) { int x = wtot[w]; wtot[w] = r; r += x; }
    }
    __syncthreads();
    int excl = incl - v + wtot[wv] + bofs[blockIdx.x];
    if (idx < N_NODES) {
        rofs[idx] = excl;
        wofs[idx] = excl;
    }
    if (idx == 0) rofs[N_NODES] = N_EDGES;
}

// ---------------------------------------------------------------------------
// Heterogeneous: blocks [0, GEMM_BLOCKS) = MFMA GEMM g = x*M; blocks
// [GEMM_BLOCKS, +EDGE_BLOCKS) = CSR scatter csr[wofs[d]++] = src.
// ---------------------------------------------------------------------------
__global__ __launch_bounds__(256, 4)
void k_main(const float* __restrict__ X, const bf16_t* __restrict__ Mbf,
            bf16_t* __restrict__ G,
            const int* __restrict__ src, const int* __restrict__ dst,
            int* __restrict__ wofs, unsigned short* __restrict__ csr) {
    const int bid = blockIdx.x;
    const int tid = threadIdx.x;

    if (bid >= GEMM_BLOCKS) {
        int e = (bid - GEMM_BLOCKS) * 256 + tid;
        if (e < N_EDGES) {
            int d = dst[e];
            int pos = atomicAdd(&wofs[d], 1);
            csr[pos] = (unsigned short)src[e];
        }
        return;
    }

    // ---- GEMM role ----
    __shared__ unsigned short Xs[64 * 128];  // bf16, swizzled
    const int row0 = bid * 64;

    for (int idx = tid; idx < 1024; idx += 256) {
        int r = idx >> 4, c = idx & 15;
        int grow = row0 + r;
        float4 va = {0.f, 0.f, 0.f, 0.f}, vb = {0.f, 0.f, 0.f, 0.f};
        if (grow < N_NODES) {
            const float4* xr = (const float4*)(X + (size_t)grow * F);
            va = xr[2 * c];
            vb = xr[2 * c + 1];
        }
        ushort8v u;
        u[0] = f2bf(va.x); u[1] = f2bf(va.y); u[2] = f2bf(va.z); u[3] = f2bf(va.w);
        u[4] = f2bf(vb.x); u[5] = f2bf(vb.y); u[6] = f2bf(vb.z); u[7] = f2bf(vb.w);
        *(ushort8v*)&Xs[r * 128 + (((c ^ (r & 7)) << 3))] = u;
    }
    __syncthreads();

    const int wid = tid >> 6;
    const int lane = tid & 63;
    const int wr = wid >> 1;
    const int wc = wid & 1;
    const int l15 = lane & 15;
    const int l4 = lane >> 4;
    const int sw = (l15 & 7);

    f32x4 acc[2][4] = {};

#pragma unroll
    for (int kc = 0; kc < 4; ++kc) {
        const int cS = ((kc * 4 + l4) ^ sw) << 3;
        short8v a0 = *(const short8v*)&Xs[(wr * 32 + 0 * 16 + l15) * 128 + cS];
        short8v a1 = *(const short8v*)&Xs[(wr * 32 + 1 * 16 + l15) * 128 + cS];
        const bf16_t* mb = Mbf + (size_t)(wc * 64 + l15) * F + kc * 32 + 8 * l4;
        short8v b0 = *(const short8v*)(mb + 0 * 16 * F);
        short8v b1 = *(const short8v*)(mb + 1 * 16 * F);
        short8v b2 = *(const short8v*)(mb + 2 * 16 * F);
        short8v b3 = *(const short8v*)(mb + 3 * 16 * F);
        acc[0][0] = __builtin_amdgcn_mfma_f32_16x16x32_bf16(a0, b0, acc[0][0], 0, 0, 0);
        acc[0][1] = __builtin_amdgcn_mfma_f32_16x16x32_bf16(a0, b1, acc[0][1], 0, 0, 0);
        acc[0][2] = __builtin_amdgcn_mfma_f32_16x16x32_bf16(a0, b2, acc[0][2], 0, 0, 0);
        acc[0][3] = __builtin_amdgcn_mfma_f32_16x16x32_bf16(a0, b3, acc[0][3], 0, 0, 0);
        acc[1][0] = __builtin_amdgcn_mfma_f32_16x16x32_bf16(a1, b0, acc[1][0], 0, 0, 0);
        acc[1][1] = __builtin_amdgcn_mfma_f32_16x16x32_bf16(a1, b1, acc[1][1], 0, 0, 0);
        acc[1][2] = __builtin_amdgcn_mfma_f32_16x16x32_bf16(a1, b2, acc[1][2], 0, 0, 0);
        acc[1][3] = __builtin_amdgcn_mfma_f32_16x16x32_bf16(a1, b3, acc[1][3], 0, 0, 0);
    }

#pragma unroll
    for (int mt = 0; mt < 2; ++mt) {
#pragma unroll
        for (int nt = 0; nt < 4; ++nt) {
#pragma unroll
            for (int r = 0; r < 4; ++r) {
                int grow = row0 + wr * 32 + mt * 16 + l4 * 4 + r;
                if (grow < N_NODES) {
                    int gcol = wc * 64 + nt * 16 + l15;
                    G[(size_t)grow * F + gcol] = f2bf(acc[mt][nt][r]);
                }
            }
        }
    }
}

// ---------------------------------------------------------------------------
// O[n] = H[n] + sum_{s in csr[rofs[n]..rofs[n+1])} H[s].  Quarter-wave
// (16 lanes x ushort8 = 256B row); 4 independent gather chains per wave.
// ---------------------------------------------------------------------------
__global__ __launch_bounds__(256)
void k_agg(const bf16_t* __restrict__ H, const int* __restrict__ rofs,
           const unsigned short* __restrict__ csr, bf16_t* __restrict__ O,
           int n_rows) {
    int tid = threadIdx.x;
    int lane = tid & 15;
    int node = blockIdx.x * 16 + (tid >> 4);
    if (node >= n_rows) return;

    int r0 = rofs[node];
    int deg = rofs[node + 1] - r0;

    ushort8v u = ((const ushort8v*)(H + (size_t)node * F))[lane];
    float a0 = bf2f(u[0]), a1 = bf2f(u[1]), a2 = bf2f(u[2]), a3 = bf2f(u[3]);
    float a4 = bf2f(u[4]), a5 = bf2f(u[5]), a6 = bf2f(u[6]), a7 = bf2f(u[7]);

    const unsigned short* bk = csr + r0;
    int i = 0;
    for (; i + 4 <= deg; i += 4) {
        int s0 = bk[i + 0], s1 = bk[i + 1], s2 = bk[i + 2], s3 = bk[i + 3];
        ushort8v u0 = ((const ushort8v*)(H + (size_t)s0 * F))[lane];
        ushort8v u1 = ((const ushort8v*)(H + (size_t)s1 * F))[lane];
        ushort8v u2 = ((const ushort8v*)(H + (size_t)s2 * F))[lane];
        ushort8v u3 = ((const ushort8v*)(H + (size_t)s3 * F))[lane];
        a0 += bf2f(u0[0]) + bf2f(u1[0]) + bf2f(u2[0]) + bf2f(u3[0]);
        a1 += bf2f(u0[1]) + bf2f(u1[1]) + bf2f(u2[1]) + bf2f(u3[1]);
        a2 += bf2f(u0[2]) + bf2f(u1[2]) + bf2f(u2[2]) + bf2f(u3[2]);
        a3 += bf2f(u0[3]) + bf2f(u1[3]) + bf2f(u2[3]) + bf2f(u3[3]);
        a4 += bf2f(u0[4]) + bf2f(u1[4]) + bf2f(u2[4]) + bf2f(u3[4]);
        a5 += bf2f(u0[5]) + bf2f(u1[5]) + bf2f(u2[5]) + bf2f(u3[5]);
        a6 += bf2f(u0[6]) + bf2f(u1[6]) + bf2f(u2[6]) + bf2f(u3[6]);
        a7 += bf2f(u0[7]) + bf2f(u1[7]) + bf2f(u2[7]) + bf2f(u3[7]);
    }
    for (; i < deg; ++i) {
        ushort8v uv = ((const ushort8v*)(H + (size_t)bk[i] * F))[lane];
        a0 += bf2f(uv[0]); a1 += bf2f(uv[1]); a2 += bf2f(uv[2]); a3 += bf2f(uv[3]);
        a4 += bf2f(uv[4]); a5 += bf2f(uv[5]); a6 += bf2f(uv[6]); a7 += bf2f(uv[7]);
    }
    ushort8v o;
    o[0] = f2bf(a0); o[1] = f2bf(a1); o[2] = f2bf(a2); o[3] = f2bf(a3);
    o[4] = f2bf(a4); o[5] = f2bf(a5); o[6] = f2bf(a6); o[7] = f2bf(a7);
    ((ushort8v*)(O + (size_t)node * F))[lane] = o;
}

// ---------------------------------------------------------------------------
// out[n] = log_softmax( (S*H)[n] + sd_n*v1 + d_n*bc ), sd inline via cnt
// gathers; softmax reduced over the 16-lane group.
// ---------------------------------------------------------------------------
__global__ __launch_bounds__(256)
void k_agg_ep(const bf16_t* __restrict__ H, const int* __restrict__ rofs,
              const unsigned short* __restrict__ csr, const int* __restrict__ cnt,
              const float* __restrict__ v1, const float* __restrict__ bc,
              float* __restrict__ O, int n_rows) {
    int tid = threadIdx.x;
    int lane = tid & 15;
    int node = blockIdx.x * 16 + (tid >> 4);
    if (node >= n_rows) return;

    int r0 = rofs[node];
    int deg = rofs[node + 1] - r0;

    ushort8v u = ((const ushort8v*)(H + (size_t)node * F))[lane];
    float a0 = bf2f(u[0]), a1 = bf2f(u[1]), a2 = bf2f(u[2]), a3 = bf2f(u[3]);
    float a4 = bf2f(u[4]), a5 = bf2f(u[5]), a6 = bf2f(u[6]), a7 = bf2f(u[7]);

    const unsigned short* bk = csr + r0;

    int sdi = (lane == 0) ? (deg + 1) : 0;
    for (int j = lane; j < deg; j += 16) sdi += cnt[bk[j]] + 1;

    int i = 0;
    for (; i + 4 <= deg; i += 4) {
        int s0 = bk[i + 0], s1 = bk[i + 1], s2 = bk[i + 2], s3 = bk[i + 3];
        ushort8v u0 = ((const ushort8v*)(H + (size_t)s0 * F))[lane];
        ushort8v u1 = ((const ushort8v*)(H + (size_t)s1 * F))[lane];
        ushort8v u2 = ((const ushort8v*)(H + (size_t)s2 * F))[lane];
        ushort8v u3 = ((const ushort8v*)(H + (size_t)s3 * F))[lane];
        a0 += bf2f(u0[0]) + bf2f(u1[0]) + bf2f(u2[0]) + bf2f(u3[0]);
        a1 += bf2f(u0[1]) + bf2f(u1[1]) + bf2f(u2[1]) + bf2f(u3[1]);
        a2 += bf2f(u0[2]) + bf2f(u1[2]) + bf2f(u2[2]) + bf2f(u3[2]);
        a3 += bf2f(u0[3]) + bf2f(u1[3]) + bf2f(u2[3]) + bf2f(u3[3]);
        a4 += bf2f(u0[4]) + bf2f(u1[4]) + bf2f(u2[4]) + bf2f(u3[4]);
        a5 += bf2f(u0[5]) + bf2f(u1[5]) + bf2f(u2[5]) + bf2f(u3[5]);
        a6 += bf2f(u0[6]) + bf2f(u1[6]) + bf2f(u2[6]) + bf2f(u3[6]);
        a7 += bf2f(u0[7]) + bf2f(u1[7]) + bf2f(u2[7]) + bf2f(u3[7]);
    }
    for (; i < deg; ++i) {
        ushort8v uv = ((const ushort8v*)(H + (size_t)bk[i] * F))[lane];
        a0 += bf2f(uv[0]); a1 += bf2f(uv[1]); a2 += bf2f(uv[2]); a3 += bf2f(uv[3]);
        a4 += bf2f(uv[4]); a5 += bf2f(uv[5]); a6 += bf2f(uv[6]); a7 += bf2f(uv[7]);
    }

#pragma unroll
    for (int o = 8; o; o >>= 1) sdi += __shfl_xor(sdi, o);
    float sdn = (float)sdi;
    float dn = (float)(deg + 1);
    float4 v1a = ((const float4*)v1)[2 * lane], v1b = ((const float4*)v1)[2 * lane + 1];
    float4 bca = ((const float4*)bc)[2 * lane], bcb = ((const float4*)bc)[2 * lane + 1];
    a0 += sdn * v1a.x + dn * bca.x;
    a1 += sdn * v1a.y + dn * bca.y;
    a2 += sdn * v1a.z + dn * bca.z;
    a3 += sdn * v1a.w + dn * bca.w;
    a4 += sdn * v1b.x + dn * bcb.x;
    a5 += sdn * v1b.y + dn * bcb.y;
    a6 += sdn * v1b.z + dn * bcb.z;
    a7 += sdn * v1b.w + dn * bcb.w;

    float m = fmaxf(fmaxf(fmaxf(a0, a1), fmaxf(a2, a3)),
                    fmaxf(fmaxf(a4, a5), fmaxf(a6, a7)));
#pragma unroll
    for (int o = 8; o; o >>= 1) m = fmaxf(m, __shfl_xor(m, o));
    float s = expf(a0 - m) + expf(a1 - m) + expf(a2 - m) + expf(a3 - m)
            + expf(a4 - m) + expf(a5 - m) + expf(a6 - m) + expf(a7 - m);
#pragma unroll
    for (int o = 8; o; o >>= 1) s += __shfl_xor(s, o);
    float lse = m + logf(s);
    float4 oa, ob;
    oa.x = a0 - lse; oa.y = a1 - lse; oa.z = a2 - lse; oa.w = a3 - lse;
    ob.x = a4 - lse; ob.y = a5 - lse; ob.z = a6 - lse; ob.w = a7 - lse;
    ((float4*)(O + (size_t)node * F))[2 * lane] = oa;
    ((float4*)(O + (size_t)node * F))[2 * lane + 1] = ob;
}

extern "C" void kernel_launch(void* const* d_in, const int* in_sizes, int n_in,
                              void* d_out, int out_size, void* d_ws, size_t ws_size,
                              hipStream_t stream) {
    const float* x  = (const float*)d_in[0];
    const int* ei   = (const int*)d_in[1];
    const float* w1 = (const float*)d_in[2];
    const float* b1 = (const float*)d_in[3];
    const float* w2 = (const float*)d_in[4];
    const float* b2 = (const float*)d_in[5];
    float* out = (float*)d_out;

    const int* src = ei;
    const int* dst = ei + N_EDGES;

    // workspace layout (float offsets, 16B aligned)
    float* ws       = (float*)d_ws;
    float* Wc       = ws;                          // 16384
    float* bc       = ws + 16384;                  // 128
    float* v1       = ws + 16512;                  // 128
    bf16_t* Mbf     = (bf16_t*)(ws + 16640);       // 16384 bf16 (8192 f)
    int*   cnt      = (int*)(ws + 24832);          // 50048
    int*   rofs     = (int*)(ws + 74880);          // 50001 (pad 50048)
    int*   wofs     = (int*)(ws + 124928);         // 50048
    int*   bsum     = (int*)(ws + 174976);         // 256
    int*   bofs     = (int*)(ws + 175232);         // 256
    unsigned short* csr = (unsigned short*)(ws + 175488);  // 600000 u16 (300000 f)
    bf16_t* g       = (bf16_t*)(ws + 475488);      // 6.4M bf16 (3.2M f)
    bf16_t* a1      = (bf16_t*)(ws + 3675488);     // 6.4M bf16

    const int node_grid = (N_NODES + 15) / 16;  // 3125

    k_fuse<<<128, 128, 0, stream>>>(w1, b1, w2, b2, Wc, bc, cnt);
    // Mbf/v1 || degree histogram
    k_fuse2h<<<128 + EDGE_BLOCKS, 256, 0, stream>>>(Wc, bc, Mbf, v1, dst, cnt);
    // hierarchical exclusive scan: cnt -> rofs/wofs
    k_scan1<<<SCAN_BLOCKS, 256, 0, stream>>>(cnt, bsum);
    k_scan2<<<1, 256, 0, stream>>>(bsum, bofs);
    k_scan3<<<SCAN_BLOCKS, 256, 0, stream>>>(cnt, bofs, rofs, wofs);
    // g = x*M (MFMA) || CSR scatter
    k_main<<<GEMM_BLOCKS + EDGE_BLOCKS, 256, 0, stream>>>(x, Mbf, g, src, dst,
                                                          wofs, csr);
    // a1 = S * g
    k_agg<<<node_grid, 256, 0, stream>>>(g, rofs, csr, a1, N_NODES);
    // out = log_softmax(S * a1 + sd*v1^T + d*bc^T)
    k_agg_ep<<<node_grid, 256, 0, stream>>>(a1, rofs, csr, cnt, v1, bc, out, N_NODES);
}

// Round 9
// 134.461 us; speedup vs baseline: 1.9662x; 1.0831x over previous
//
#include <hip/hip_runtime.h>
#include <hip/hip_bf16.h>

#define N_NODES 50000
#define N_EDGES 600000
#define F 128

#define GEMM_BLOCKS 782   // ceil(50000/64)
#define NBINS 196         // ceil(50000/256), bin = dst >> 8
#define NHB 128           // histogram/scatter blocks
#define EPB 4688          // edges per hist/scatter block (128*4688 >= 600000)

typedef unsigned short bf16_t;
typedef __attribute__((ext_vector_type(8))) short short8v;
typedef __attribute__((ext_vector_type(8))) unsigned short ushort8v;
typedef __attribute__((ext_vector_type(4))) float f32x4;

__device__ inline float bf2f(bf16_t u) {
    union { unsigned int i; float f; } c;
    c.i = ((unsigned int)u) << 16;
    return c.f;
}
__device__ inline bf16_t f2bf(float f) {  // round-to-nearest-even
    union { float f; unsigned int i; } c;
    c.f = f;
    unsigned int lsb = (c.i >> 16) & 1;
    c.i += 0x7fffu + lsb;
    return (bf16_t)(c.i >> 16);
}

// ---------------------------------------------------------------------------
// Wc = w2 @ w1 (plain [p][j]), bc = w2@b1 + b2.
// ---------------------------------------------------------------------------
__global__ void k_fuse(const float* __restrict__ w1, const float* __restrict__ b1,
                       const float* __restrict__ w2, const float* __restrict__ b2,
                       float* __restrict__ Wc, float* __restrict__ bc) {
    int p = blockIdx.x;
    int j = threadIdx.x;
    float s = 0.f;
    for (int o = 0; o < F; ++o) s = fmaf(w2[p * F + o], w1[o * F + j], s);
    Wc[p * F + j] = s;
    if (j == 0) {
        float t = b2[p];
        for (int o = 0; o < F; ++o) t = fmaf(w2[p * F + o], b1[o], t);
        bc[p] = t;
    }
}

// ---------------------------------------------------------------------------
// Heterogeneous: blocks [0,128) compute Mbf[p][k] = (W^T W^T)[k][p] (bf16,
// B-operand layout) and v1 = Wc*bc; blocks [128, 128+NHB) run passA: per-block
// LDS coarse histogram of dst>>8, written to cnt2[bin*NHB + blk] (no global
// atomics).
// ---------------------------------------------------------------------------
__global__ __launch_bounds__(256)
void k_fuse2h(const float* __restrict__ Wc, const float* __restrict__ bc,
              bf16_t* __restrict__ Mbf, float* __restrict__ v1,
              const int* __restrict__ dst, int* __restrict__ cnt2) {
    int bid = blockIdx.x;
    int tid = threadIdx.x;
    if (bid < 128) {
        if (tid < 128) {
            int k = bid, p = tid;
            float s = 0.f;
            for (int o = 0; o < F; ++o) s = fmaf(Wc[p * F + o], Wc[o * F + k], s);
            Mbf[p * F + k] = f2bf(s);
            if (k == 0) {
                float t = 0.f;
                for (int o = 0; o < F; ++o) t = fmaf(Wc[p * F + o], bc[o], t);
                v1[p] = t;
            }
        }
        return;
    }
    __shared__ int hist[NBINS];
    int hb = bid - 128;
    for (int b = tid; b < NBINS; b += 256) hist[b] = 0;
    __syncthreads();
    int e0 = hb * EPB;
    int e1 = min(e0 + EPB, N_EDGES);
    for (int e = e0 + tid; e < e1; e += 256) atomicAdd(&hist[dst[e] >> 8], 1);
    __syncthreads();
    for (int b = tid; b < NBINS; b += 256) cnt2[b * NHB + hb] = hist[b];
}

// ---------------------------------------------------------------------------
// Exclusive scan of cnt2[NBINS*NHB] -> wofs2 (per-(bin,block) write bases)
// and binofs[b] (global bin starts). One 1024-thread block, all-parallel.
// ---------------------------------------------------------------------------
__global__ __launch_bounds__(1024)
void k_binscan(const int* __restrict__ cnt2, int* __restrict__ wofs2,
               int* __restrict__ binofs) {
    __shared__ int wtot[16];
    const int NV = NBINS * NHB;  // 25088
    const int CH = 25;           // 1024*25 = 25600 >= NV
    int t = threadIdx.x;
    int lane = t & 63, wv = t >> 6;
    int base = t * CH;
    int s = 0;
    for (int i = 0; i < CH; ++i) {
        int idx = base + i;
        if (idx < NV) s += cnt2[idx];
    }
    int incl = s;
#pragma unroll
    for (int o = 1; o < 64; o <<= 1) {
        int u = __shfl_up(incl, o);
        if (lane >= o) incl += u;
    }
    if (lane == 63) wtot[wv] = incl;
    __syncthreads();
    if (t == 0) {
        int r = 0;
        for (int w = 0; w < 16; ++w) { int x = wtot[w]; wtot[w] = r; r += x; }
    }
    __syncthreads();
    int run = incl - s + wtot[wv];
    for (int i = 0; i < CH; ++i) {
        int idx = base + i;
        if (idx < NV) {
            int w = cnt2[idx];
            wofs2[idx] = run;
            if ((idx & (NHB - 1)) == 0) binofs[idx >> 7] = run;
            run += w;
        }
    }
    if (t == 0) binofs[NBINS] = N_EDGES;
}

// ---------------------------------------------------------------------------
// Heterogeneous: blocks [0, GEMM_BLOCKS) = MFMA GEMM g = x*M; blocks
// [GEMM_BLOCKS, +NHB) = passB: binned scatter of (dlow8,src) pairs into
// block-private contiguous sub-ranges (LDS cursors, no global atomics).
// ---------------------------------------------------------------------------
__global__ __launch_bounds__(256, 4)
void k_mainB(const float* __restrict__ X, const bf16_t* __restrict__ Mbf,
             bf16_t* __restrict__ G,
             const int* __restrict__ src, const int* __restrict__ dst,
             const int* __restrict__ wofs2, unsigned int* __restrict__ ebuf) {
    const int bid = blockIdx.x;
    const int tid = threadIdx.x;

    if (bid >= GEMM_BLOCKS) {
        __shared__ int cur[NBINS];
        int hb = bid - GEMM_BLOCKS;
        for (int b = tid; b < NBINS; b += 256) cur[b] = wofs2[b * NHB + hb];
        __syncthreads();
        int e0 = hb * EPB;
        int e1 = min(e0 + EPB, N_EDGES);
        for (int e = e0 + tid; e < e1; e += 256) {
            int d = dst[e];
            int s = src[e];
            int b = d >> 8;
            int pos = atomicAdd(&cur[b], 1);  // LDS atomic
            ebuf[pos] = ((unsigned int)(d & 255) << 16) | (unsigned int)s;
        }
        return;
    }

    // ---- GEMM role ----
    __shared__ unsigned short Xs[64 * 128];  // bf16, swizzled
    const int row0 = bid * 64;

    for (int idx = tid; idx < 1024; idx += 256) {
        int r = idx >> 4, c = idx & 15;
        int grow = row0 + r;
        float4 va = {0.f, 0.f, 0.f, 0.f}, vb = {0.f, 0.f, 0.f, 0.f};
        if (grow < N_NODES) {
            const float4* xr = (const float4*)(X + (size_t)grow * F);
            va = xr[2 * c];
            vb = xr[2 * c + 1];
        }
        ushort8v u;
        u[0] = f2bf(va.x); u[1] = f2bf(va.y); u[2] = f2bf(va.z); u[3] = f2bf(va.w);
        u[4] = f2bf(vb.x); u[5] = f2bf(vb.y); u[6] = f2bf(vb.z); u[7] = f2bf(vb.w);
        *(ushort8v*)&Xs[r * 128 + (((c ^ (r & 7)) << 3))] = u;
    }
    __syncthreads();

    const int wid = tid >> 6;
    const int lane = tid & 63;
    const int wr = wid >> 1;
    const int wc = wid & 1;
    const int l15 = lane & 15;
    const int l4 = lane >> 4;
    const int sw = (l15 & 7);

    f32x4 acc[2][4] = {};

#pragma unroll
    for (int kc = 0; kc < 4; ++kc) {
        const int cS = ((kc * 4 + l4) ^ sw) << 3;
        short8v a0 = *(const short8v*)&Xs[(wr * 32 + 0 * 16 + l15) * 128 + cS];
        short8v a1 = *(const short8v*)&Xs[(wr * 32 + 1 * 16 + l15) * 128 + cS];
        const bf16_t* mb = Mbf + (size_t)(wc * 64 + l15) * F + kc * 32 + 8 * l4;
        short8v b0 = *(const short8v*)(mb + 0 * 16 * F);
        short8v b1 = *(const short8v*)(mb + 1 * 16 * F);
        short8v b2 = *(const short8v*)(mb + 2 * 16 * F);
        short8v b3 = *(const short8v*)(mb + 3 * 16 * F);
        acc[0][0] = __builtin_amdgcn_mfma_f32_16x16x32_bf16(a0, b0, acc[0][0], 0, 0, 0);
        acc[0][1] = __builtin_amdgcn_mfma_f32_16x16x32_bf16(a0, b1, acc[0][1], 0, 0, 0);
        acc[0][2] = __builtin_amdgcn_mfma_f32_16x16x32_bf16(a0, b2, acc[0][2], 0, 0, 0);
        acc[0][3] = __builtin_amdgcn_mfma_f32_16x16x32_bf16(a0, b3, acc[0][3], 0, 0, 0);
        acc[1][0] = __builtin_amdgcn_mfma_f32_16x16x32_bf16(a1, b0, acc[1][0], 0, 0, 0);
        acc[1][1] = __builtin_amdgcn_mfma_f32_16x16x32_bf16(a1, b1, acc[1][1], 0, 0, 0);
        acc[1][2] = __builtin_amdgcn_mfma_f32_16x16x32_bf16(a1, b2, acc[1][2], 0, 0, 0);
        acc[1][3] = __builtin_amdgcn_mfma_f32_16x16x32_bf16(a1, b3, acc[1][3], 0, 0, 0);
    }

#pragma unroll
    for (int mt = 0; mt < 2; ++mt) {
#pragma unroll
        for (int nt = 0; nt < 4; ++nt) {
#pragma unroll
            for (int r = 0; r < 4; ++r) {
                int grow = row0 + wr * 32 + mt * 16 + l4 * 4 + r;
                if (grow < N_NODES) {
                    int gcol = wc * 64 + nt * 16 + l15;
                    G[(size_t)grow * F + gcol] = f2bf(acc[mt][nt][r]);
                }
            }
        }
    }
}

// ---------------------------------------------------------------------------
// Per-bin finalize: LDS per-node histogram + scan -> cnt[], rofs[] (global
// offsets = binofs[b] + local scan), then scatter src into the bin's
// contiguous csr slice (LDS cursors).
// ---------------------------------------------------------------------------
__global__ __launch_bounds__(256)
void k_fine(const unsigned int* __restrict__ ebuf, const int* __restrict__ binofs,
            int* __restrict__ cnt, int* __restrict__ rofs,
            unsigned short* __restrict__ csr) {
    __shared__ int hcnt[256];
    __shared__ int cur2[256];
    __shared__ int wtot[4];
    int b = blockIdx.x, t = threadIdx.x;
    int r0 = binofs[b];
    int m = binofs[b + 1] - r0;

    hcnt[t] = 0;
    __syncthreads();
    for (int i = t; i < m; i += 256) atomicAdd(&hcnt[ebuf[r0 + i] >> 16], 1);
    __syncthreads();

    int v = hcnt[t];
    int lane = t & 63, wv = t >> 6;
    int incl = v;
#pragma unroll
    for (int o = 1; o < 64; o <<= 1) {
        int u = __shfl_up(incl, o);
        if (lane >= o) incl += u;
    }
    if (lane == 63) wtot[wv] = incl;
    __syncthreads();
    if (t == 0) {
        int r = 0;
        for (int w = 0; w < 4; ++w) { int x = wtot[w]; wtot[w] = r; r += x; }
    }
    __syncthreads();
    int excl = incl - v + wtot[wv];

    int node = b * 256 + t;
    if (node < N_NODES) { cnt[node] = v; rofs[node] = r0 + excl; }
    if (node == N_NODES) rofs[N_NODES] = N_EDGES;
    cur2[t] = excl;
    __syncthreads();

    for (int i = t; i < m; i += 256) {
        unsigned int u = ebuf[r0 + i];
        int d8 = u >> 16;
        int s = u & 0xFFFF;
        int slot = atomicAdd(&cur2[d8], 1);  // LDS atomic
        csr[r0 + slot] = (unsigned short)s;
    }
}

// ---------------------------------------------------------------------------
// O[n] = H[n] + sum_{s in csr[rofs[n]..rofs[n+1])} H[s].  Quarter-wave
// (16 lanes x ushort8 = 256B row); 4 independent gather chains per wave.
// ---------------------------------------------------------------------------
__global__ __launch_bounds__(256)
void k_agg(const bf16_t* __restrict__ H, const int* __restrict__ rofs,
           const unsigned short* __restrict__ csr, bf16_t* __restrict__ O,
           int n_rows) {
    int tid = threadIdx.x;
    int lane = tid & 15;
    int node = blockIdx.x * 16 + (tid >> 4);
    if (node >= n_rows) return;

    int r0 = rofs[node];
    int deg = rofs[node + 1] - r0;

    ushort8v u = ((const ushort8v*)(H + (size_t)node * F))[lane];
    float a0 = bf2f(u[0]), a1 = bf2f(u[1]), a2 = bf2f(u[2]), a3 = bf2f(u[3]);
    float a4 = bf2f(u[4]), a5 = bf2f(u[5]), a6 = bf2f(u[6]), a7 = bf2f(u[7]);

    const unsigned short* bk = csr + r0;
    int i = 0;
    for (; i + 4 <= deg; i += 4) {
        int s0 = bk[i + 0], s1 = bk[i + 1], s2 = bk[i + 2], s3 = bk[i + 3];
        ushort8v u0 = ((const ushort8v*)(H + (size_t)s0 * F))[lane];
        ushort8v u1 = ((const ushort8v*)(H + (size_t)s1 * F))[lane];
        ushort8v u2 = ((const ushort8v*)(H + (size_t)s2 * F))[lane];
        ushort8v u3 = ((const ushort8v*)(H + (size_t)s3 * F))[lane];
        a0 += bf2f(u0[0]) + bf2f(u1[0]) + bf2f(u2[0]) + bf2f(u3[0]);
        a1 += bf2f(u0[1]) + bf2f(u1[1]) + bf2f(u2[1]) + bf2f(u3[1]);
        a2 += bf2f(u0[2]) + bf2f(u1[2]) + bf2f(u2[2]) + bf2f(u3[2]);
        a3 += bf2f(u0[3]) + bf2f(u1[3]) + bf2f(u2[3]) + bf2f(u3[3]);
        a4 += bf2f(u0[4]) + bf2f(u1[4]) + bf2f(u2[4]) + bf2f(u3[4]);
        a5 += bf2f(u0[5]) + bf2f(u1[5]) + bf2f(u2[5]) + bf2f(u3[5]);
        a6 += bf2f(u0[6]) + bf2f(u1[6]) + bf2f(u2[6]) + bf2f(u3[6]);
        a7 += bf2f(u0[7]) + bf2f(u1[7]) + bf2f(u2[7]) + bf2f(u3[7]);
    }
    for (; i < deg; ++i) {
        ushort8v uv = ((const ushort8v*)(H + (size_t)bk[i] * F))[lane];
        a0 += bf2f(uv[0]); a1 += bf2f(uv[1]); a2 += bf2f(uv[2]); a3 += bf2f(uv[3]);
        a4 += bf2f(uv[4]); a5 += bf2f(uv[5]); a6 += bf2f(uv[6]); a7 += bf2f(uv[7]);
    }
    ushort8v o;
    o[0] = f2bf(a0); o[1] = f2bf(a1); o[2] = f2bf(a2); o[3] = f2bf(a3);
    o[4] = f2bf(a4); o[5] = f2bf(a5); o[6] = f2bf(a6); o[7] = f2bf(a7);
    ((ushort8v*)(O + (size_t)node * F))[lane] = o;
}

// ---------------------------------------------------------------------------
// out[n] = log_softmax( (S*H)[n] + sd_n*v1 + d_n*bc ), sd inline via cnt
// gathers; softmax reduced over the 16-lane group.
// ---------------------------------------------------------------------------
__global__ __launch_bounds__(256)
void k_agg_ep(const bf16_t* __restrict__ H, const int* __restrict__ rofs,
              const unsigned short* __restrict__ csr, const int* __restrict__ cnt,
              const float* __restrict__ v1, const float* __restrict__ bc,
              float* __restrict__ O, int n_rows) {
    int tid = threadIdx.x;
    int lane = tid & 15;
    int node = blockIdx.x * 16 + (tid >> 4);
    if (node >= n_rows) return;

    int r0 = rofs[node];
    int deg = rofs[node + 1] - r0;

    ushort8v u = ((const ushort8v*)(H + (size_t)node * F))[lane];
    float a0 = bf2f(u[0]), a1 = bf2f(u[1]), a2 = bf2f(u[2]), a3 = bf2f(u[3]);
    float a4 = bf2f(u[4]), a5 = bf2f(u[5]), a6 = bf2f(u[6]), a7 = bf2f(u[7]);

    const unsigned short* bk = csr + r0;

    int sdi = (lane == 0) ? (deg + 1) : 0;
    for (int j = lane; j < deg; j += 16) sdi += cnt[bk[j]] + 1;

    int i = 0;
    for (; i + 4 <= deg; i += 4) {
        int s0 = bk[i + 0], s1 = bk[i + 1], s2 = bk[i + 2], s3 = bk[i + 3];
        ushort8v u0 = ((const ushort8v*)(H + (size_t)s0 * F))[lane];
        ushort8v u1 = ((const ushort8v*)(H + (size_t)s1 * F))[lane];
        ushort8v u2 = ((const ushort8v*)(H + (size_t)s2 * F))[lane];
        ushort8v u3 = ((const ushort8v*)(H + (size_t)s3 * F))[lane];
        a0 += bf2f(u0[0]) + bf2f(u1[0]) + bf2f(u2[0]) + bf2f(u3[0]);
        a1 += bf2f(u0[1]) + bf2f(u1[1]) + bf2f(u2[1]) + bf2f(u3[1]);
        a2 += bf2f(u0[2]) + bf2f(u1[2]) + bf2f(u2[2]) + bf2f(u3[2]);
        a3 += bf2f(u0[3]) + bf2f(u1[3]) + bf2f(u2[3]) + bf2f(u3[3]);
        a4 += bf2f(u0[4]) + bf2f(u1[4]) + bf2f(u2[4]) + bf2f(u3[4]);
        a5 += bf2f(u0[5]) + bf2f(u1[5]) + bf2f(u2[5]) + bf2f(u3[5]);
        a6 += bf2f(u0[6]) + bf2f(u1[6]) + bf2f(u2[6]) + bf2f(u3[6]);
        a7 += bf2f(u0[7]) + bf2f(u1[7]) + bf2f(u2[7]) + bf2f(u3[7]);
    }
    for (; i < deg; ++i) {
        ushort8v uv = ((const ushort8v*)(H + (size_t)bk[i] * F))[lane];
        a0 += bf2f(uv[0]); a1 += bf2f(uv[1]); a2 += bf2f(uv[2]); a3 += bf2f(uv[3]);
        a4 += bf2f(uv[4]); a5 += bf2f(uv[5]); a6 += bf2f(uv[6]); a7 += bf2f(uv[7]);
    }

#pragma unroll
    for (int o = 8; o; o >>= 1) sdi += __shfl_xor(sdi, o);
    float sdn = (float)sdi;
    float dn = (float)(deg + 1);
    float4 v1a = ((const float4*)v1)[2 * lane], v1b = ((const float4*)v1)[2 * lane + 1];
    float4 bca = ((const float4*)bc)[2 * lane], bcb = ((const float4*)bc)[2 * lane + 1];
    a0 += sdn * v1a.x + dn * bca.x;
    a1 += sdn * v1a.y + dn * bca.y;
    a2 += sdn * v1a.z + dn * bca.z;
    a3 += sdn * v1a.w + dn * bca.w;
    a4 += sdn * v1b.x + dn * bcb.x;
    a5 += sdn * v1b.y + dn * bcb.y;
    a6 += sdn * v1b.z + dn * bcb.z;
    a7 += sdn * v1b.w + dn * bcb.w;

    float m = fmaxf(fmaxf(fmaxf(a0, a1), fmaxf(a2, a3)),
                    fmaxf(fmaxf(a4, a5), fmaxf(a6, a7)));
#pragma unroll
    for (int o = 8; o; o >>= 1) m = fmaxf(m, __shfl_xor(m, o));
    float s = expf(a0 - m) + expf(a1 - m) + expf(a2 - m) + expf(a3 - m)
            + expf(a4 - m) + expf(a5 - m) + expf(a6 - m) + expf(a7 - m);
#pragma unroll
    for (int o = 8; o; o >>= 1) s += __shfl_xor(s, o);
    float lse = m + logf(s);
    float4 oa, ob;
    oa.x = a0 - lse; oa.y = a1 - lse; oa.z = a2 - lse; oa.w = a3 - lse;
    ob.x = a4 - lse; ob.y = a5 - lse; ob.z = a6 - lse; ob.w = a7 - lse;
    ((float4*)(O + (size_t)node * F))[2 * lane] = oa;
    ((float4*)(O + (size_t)node * F))[2 * lane + 1] = ob;
}

extern "C" void kernel_launch(void* const* d_in, const int* in_sizes, int n_in,
                              void* d_out, int out_size, void* d_ws, size_t ws_size,
                              hipStream_t stream) {
    const float* x  = (const float*)d_in[0];
    const int* ei   = (const int*)d_in[1];
    const float* w1 = (const float*)d_in[2];
    const float* b1 = (const float*)d_in[3];
    const float* w2 = (const float*)d_in[4];
    const float* b2 = (const float*)d_in[5];
    float* out = (float*)d_out;

    const int* src = ei;
    const int* dst = ei + N_EDGES;

    // workspace layout (float offsets, 16B aligned)
    float* ws        = (float*)d_ws;
    float* Wc        = ws;                          // 16384
    float* bc        = ws + 16384;                  // 128
    float* v1        = ws + 16512;                  // 128
    bf16_t* Mbf      = (bf16_t*)(ws + 16640);       // 16384 bf16 (8192 f)
    int*   cnt       = (int*)(ws + 24832);          // 50048
    int*   rofs      = (int*)(ws + 74880);          // 50001 (pad 50048)
    int*   cnt2      = (int*)(ws + 124928);         // 25088
    int*   wofs2     = (int*)(ws + 150016);         // 25088
    int*   binofs    = (int*)(ws + 175104);         // 197 (pad 256)
    unsigned int* ebuf = (unsigned int*)(ws + 175360);     // 600000 u32
    unsigned short* csr = (unsigned short*)(ws + 775360);  // 600000 u16 (300000 f)
    bf16_t* g        = (bf16_t*)(ws + 1075360);     // 6.4M bf16 (3.2M f)
    bf16_t* a1       = (bf16_t*)(ws + 4275360);     // 6.4M bf16

    const int node_grid = (N_NODES + 15) / 16;  // 3125

    k_fuse<<<128, 128, 0, stream>>>(w1, b1, w2, b2, Wc, bc);
    // Mbf/v1 || passA coarse bin histogram
    k_fuse2h<<<128 + NHB, 256, 0, stream>>>(Wc, bc, Mbf, v1, dst, cnt2);
    // scan per-(bin,block) counts -> write cursors + bin offsets
    k_binscan<<<1, 1024, 0, stream>>>(cnt2, wofs2, binofs);
    // g = x*M (MFMA) || passB binned pair scatter (block-private ranges)
    k_mainB<<<GEMM_BLOCKS + NHB, 256, 0, stream>>>(x, Mbf, g, src, dst,
                                                   wofs2, ebuf);
    // per-bin: node histogram+scan -> cnt/rofs, scatter src into csr slice
    k_fine<<<NBINS, 256, 0, stream>>>(ebuf, binofs, cnt, rofs, csr);
    // a1 = S * g
    k_agg<<<node_grid, 256, 0, stream>>>(g, rofs, csr, a1, N_NODES);
    // out = log_softmax(S * a1 + sd*v1^T + d*bc^T)
    k_agg_ep<<<node_grid, 256, 0, stream>>>(a1, rofs, csr, cnt, v1, bc, out, N_NODES);
}

// Round 10
// 121.463 us; speedup vs baseline: 2.1766x; 1.1070x over previous
//
#include <hip/hip_runtime.h>
#include <hip/hip_bf16.h>

#define N_NODES 50000
#define N_EDGES 600000
#define F 128

#define GEMM_BLOCKS 782   // ceil(50000/64)
#define NBINS 196         // ceil(50000/256), bin = dst >> 8
#define NHB 64            // histogram/scatter blocks
#define EPB 9375          // edges per hist/scatter block (64*9375 == 600000)

typedef unsigned short bf16_t;
typedef __attribute__((ext_vector_type(8))) short short8v;
typedef __attribute__((ext_vector_type(8))) unsigned short ushort8v;
typedef __attribute__((ext_vector_type(4))) float f32x4;

__device__ inline float bf2f(bf16_t u) {
    union { unsigned int i; float f; } c;
    c.i = ((unsigned int)u) << 16;
    return c.f;
}
__device__ inline bf16_t f2bf(float f) {  // round-to-nearest-even
    union { float f; unsigned int i; } c;
    c.f = f;
    unsigned int lsb = (c.i >> 16) & 1;
    c.i += 0x7fffu + lsb;
    return (bf16_t)(c.i >> 16);
}

// ---------------------------------------------------------------------------
// Wc = w2 @ w1 (plain [p][j]), bc = w2@b1 + b2.
// ---------------------------------------------------------------------------
__global__ void k_fuse(const float* __restrict__ w1, const float* __restrict__ b1,
                       const float* __restrict__ w2, const float* __restrict__ b2,
                       float* __restrict__ Wc, float* __restrict__ bc) {
    int p = blockIdx.x;
    int j = threadIdx.x;
    float s = 0.f;
    for (int o = 0; o < F; ++o) s = fmaf(w2[p * F + o], w1[o * F + j], s);
    Wc[p * F + j] = s;
    if (j == 0) {
        float t = b2[p];
        for (int o = 0; o < F; ++o) t = fmaf(w2[p * F + o], b1[o], t);
        bc[p] = t;
    }
}

// ---------------------------------------------------------------------------
// Heterogeneous: blocks [0,128) compute Mbf[p][k] = (W^T W^T)[k][p] (bf16,
// B-operand layout) and v1 = Wc*bc; blocks [128, 128+NHB) run passA: per-block
// LDS coarse histogram of dst>>8, written to cnt2[bin*NHB + blk].
// ---------------------------------------------------------------------------
__global__ __launch_bounds__(256)
void k_fuse2h(const float* __restrict__ Wc, const float* __restrict__ bc,
              bf16_t* __restrict__ Mbf, float* __restrict__ v1,
              const int* __restrict__ dst, int* __restrict__ cnt2) {
    int bid = blockIdx.x;
    int tid = threadIdx.x;
    if (bid < 128) {
        if (tid < 128) {
            int k = bid, p = tid;
            float s = 0.f;
            for (int o = 0; o < F; ++o) s = fmaf(Wc[p * F + o], Wc[o * F + k], s);
            Mbf[p * F + k] = f2bf(s);
            if (k == 0) {
                float t = 0.f;
                for (int o = 0; o < F; ++o) t = fmaf(Wc[p * F + o], bc[o], t);
                v1[p] = t;
            }
        }
        return;
    }
    __shared__ int hist[NBINS];
    int hb = bid - 128;
    for (int b = tid; b < NBINS; b += 256) hist[b] = 0;
    __syncthreads();
    int e0 = hb * EPB;
    int e1 = min(e0 + EPB, N_EDGES);
    for (int e = e0 + tid; e < e1; e += 256) atomicAdd(&hist[dst[e] >> 8], 1);
    __syncthreads();
    for (int b = tid; b < NBINS; b += 256) cnt2[b * NHB + hb] = hist[b];
}

// ---------------------------------------------------------------------------
// Exclusive scan of cnt2[NBINS*NHB] -> wofs2 (per-(bin,block) write bases)
// and binofs[b] (global bin starts). One 1024-thread block, all-parallel.
// ---------------------------------------------------------------------------
__global__ __launch_bounds__(1024)
void k_binscan(const int* __restrict__ cnt2, int* __restrict__ wofs2,
               int* __restrict__ binofs) {
    __shared__ int wtot[16];
    const int NV = NBINS * NHB;  // 12544
    const int CH = 13;           // 1024*13 = 13312 >= NV
    int t = threadIdx.x;
    int lane = t & 63, wv = t >> 6;
    int base = t * CH;
    int s = 0;
    for (int i = 0; i < CH; ++i) {
        int idx = base + i;
        if (idx < NV) s += cnt2[idx];
    }
    int incl = s;
#pragma unroll
    for (int o = 1; o < 64; o <<= 1) {
        int u = __shfl_up(incl, o);
        if (lane >= o) incl += u;
    }
    if (lane == 63) wtot[wv] = incl;
    __syncthreads();
    if (t == 0) {
        int r = 0;
        for (int w = 0; w < 16; ++w) { int x = wtot[w]; wtot[w] = r; r += x; }
    }
    __syncthreads();
    int run = incl - s + wtot[wv];
    for (int i = 0; i < CH; ++i) {
        int idx = base + i;
        if (idx < NV) {
            int w = cnt2[idx];
            wofs2[idx] = run;
            if ((idx & (NHB - 1)) == 0) binofs[idx / NHB] = run;
            run += w;
        }
    }
    if (t == 0) binofs[NBINS] = N_EDGES;
}

// ---------------------------------------------------------------------------
// Heterogeneous: blocks [0, GEMM_BLOCKS) = MFMA GEMM g = x*M; blocks
// [GEMM_BLOCKS, +NHB) = passB: LDS counting-sort of the block's edges by bin,
// then GROUPED flush — consecutive threads write consecutive ebuf addresses
// within each (bin,block) chunk (no scattered 4B stores, no line bouncing).
// LDS is a union: GEMM uses 16KB Xs; passB uses 37.5KB pairs + cursors.
// ---------------------------------------------------------------------------
__global__ __launch_bounds__(256, 4)
void k_mainB(const float* __restrict__ X, const bf16_t* __restrict__ Mbf,
             bf16_t* __restrict__ G,
             const int* __restrict__ src, const int* __restrict__ dst,
             const int* __restrict__ cnt2, const int* __restrict__ wofs2,
             unsigned int* __restrict__ ebuf) {
    __shared__ __align__(16) unsigned char smem[EPB * 4 + 3 * NBINS * 4 + 16];
    const int bid = blockIdx.x;
    const int tid = threadIdx.x;

    if (bid >= GEMM_BLOCKS) {
        // ---- passB role ----
        unsigned int* pairs = (unsigned int*)smem;
        int* cur  = (int*)(smem + EPB * 4);
        int* lofs = cur + NBINS;
        int* gofs = lofs + NBINS;
        int* wt4  = gofs + NBINS;  // 4 ints
        int hb = bid - GEMM_BLOCKS;

        // local counts + global chunk starts; exclusive scan of counts
        int c = 0;
        if (tid < NBINS) {
            c = cnt2[tid * NHB + hb];
            gofs[tid] = wofs2[tid * NHB + hb];
        }
        int lane = tid & 63, wv = tid >> 6;
        int incl = c;
#pragma unroll
        for (int o = 1; o < 64; o <<= 1) {
            int u = __shfl_up(incl, o);
            if (lane >= o) incl += u;
        }
        if (lane == 63) wt4[wv] = incl;
        __syncthreads();
        if (tid == 0) {
            int r = 0;
            for (int w = 0; w < 4; ++w) { int x = wt4[w]; wt4[w] = r; r += x; }
        }
        __syncthreads();
        if (tid < NBINS) {
            int e = incl - c + wt4[wv];
            lofs[tid] = e;
            cur[tid] = e;
        }
        __syncthreads();

        // scatter into LDS, sorted by bin
        int e0 = hb * EPB;
        for (int e = e0 + tid; e < e0 + EPB; e += 256) {
            int d = dst[e];
            int s = src[e];
            unsigned int p = ((unsigned int)d << 16) | (unsigned int)s;
            int slot = atomicAdd(&cur[d >> 8], 1);  // LDS atomic
            pairs[slot] = p;
        }
        __syncthreads();

        // grouped flush: chunk for bin b goes to gofs[b] + (i - lofs[b])
        for (int i = tid; i < EPB; i += 256) {
            unsigned int p = pairs[i];
            int b = p >> 24;  // (d>>8), d < 50000 < 2^16
            ebuf[gofs[b] + (i - lofs[b])] = p;
        }
        return;
    }

    // ---- GEMM role ----
    unsigned short* Xs = (unsigned short*)smem;  // [64][128] bf16, swizzled
    const int row0 = bid * 64;

    for (int idx = tid; idx < 1024; idx += 256) {
        int r = idx >> 4, c = idx & 15;
        int grow = row0 + r;
        float4 va = {0.f, 0.f, 0.f, 0.f}, vb = {0.f, 0.f, 0.f, 0.f};
        if (grow < N_NODES) {
            const float4* xr = (const float4*)(X + (size_t)grow * F);
            va = xr[2 * c];
            vb = xr[2 * c + 1];
        }
        ushort8v u;
        u[0] = f2bf(va.x); u[1] = f2bf(va.y); u[2] = f2bf(va.z); u[3] = f2bf(va.w);
        u[4] = f2bf(vb.x); u[5] = f2bf(vb.y); u[6] = f2bf(vb.z); u[7] = f2bf(vb.w);
        *(ushort8v*)&Xs[r * 128 + (((c ^ (r & 7)) << 3))] = u;
    }
    __syncthreads();

    const int wid = tid >> 6;
    const int lane = tid & 63;
    const int wr = wid >> 1;
    const int wc = wid & 1;
    const int l15 = lane & 15;
    const int l4 = lane >> 4;
    const int sw = (l15 & 7);

    f32x4 acc[2][4] = {};

#pragma unroll
    for (int kc = 0; kc < 4; ++kc) {
        const int cS = ((kc * 4 + l4) ^ sw) << 3;
        short8v a0 = *(const short8v*)&Xs[(wr * 32 + 0 * 16 + l15) * 128 + cS];
        short8v a1 = *(const short8v*)&Xs[(wr * 32 + 1 * 16 + l15) * 128 + cS];
        const bf16_t* mb = Mbf + (size_t)(wc * 64 + l15) * F + kc * 32 + 8 * l4;
        short8v b0 = *(const short8v*)(mb + 0 * 16 * F);
        short8v b1 = *(const short8v*)(mb + 1 * 16 * F);
        short8v b2 = *(const short8v*)(mb + 2 * 16 * F);
        short8v b3 = *(const short8v*)(mb + 3 * 16 * F);
        acc[0][0] = __builtin_amdgcn_mfma_f32_16x16x32_bf16(a0, b0, acc[0][0], 0, 0, 0);
        acc[0][1] = __builtin_amdgcn_mfma_f32_16x16x32_bf16(a0, b1, acc[0][1], 0, 0, 0);
        acc[0][2] = __builtin_amdgcn_mfma_f32_16x16x32_bf16(a0, b2, acc[0][2], 0, 0, 0);
        acc[0][3] = __builtin_amdgcn_mfma_f32_16x16x32_bf16(a0, b3, acc[0][3], 0, 0, 0);
        acc[1][0] = __builtin_amdgcn_mfma_f32_16x16x32_bf16(a1, b0, acc[1][0], 0, 0, 0);
        acc[1][1] = __builtin_amdgcn_mfma_f32_16x16x32_bf16(a1, b1, acc[1][1], 0, 0, 0);
        acc[1][2] = __builtin_amdgcn_mfma_f32_16x16x32_bf16(a1, b2, acc[1][2], 0, 0, 0);
        acc[1][3] = __builtin_amdgcn_mfma_f32_16x16x32_bf16(a1, b3, acc[1][3], 0, 0, 0);
    }

#pragma unroll
    for (int mt = 0; mt < 2; ++mt) {
#pragma unroll
        for (int nt = 0; nt < 4; ++nt) {
#pragma unroll
            for (int r = 0; r < 4; ++r) {
                int grow = row0 + wr * 32 + mt * 16 + l4 * 4 + r;
                if (grow < N_NODES) {
                    int gcol = wc * 64 + nt * 16 + l15;
                    G[(size_t)grow * F + gcol] = f2bf(acc[mt][nt][r]);
                }
            }
        }
    }
}

// ---------------------------------------------------------------------------
// Per-bin finalize: LDS per-node histogram + scan -> cnt[], rofs[] (global
// offsets = binofs[b] + local scan), then scatter src into the bin's
// contiguous csr slice (LDS cursors).
// ---------------------------------------------------------------------------
__global__ __launch_bounds__(256)
void k_fine(const unsigned int* __restrict__ ebuf, const int* __restrict__ binofs,
            int* __restrict__ cnt, int* __restrict__ rofs,
            unsigned short* __restrict__ csr) {
    __shared__ int hcnt[256];
    __shared__ int cur2[256];
    __shared__ int wtot[4];
    int b = blockIdx.x, t = threadIdx.x;
    int r0 = binofs[b];
    int m = binofs[b + 1] - r0;

    hcnt[t] = 0;
    __syncthreads();
    for (int i = t; i < m; i += 256) atomicAdd(&hcnt[(ebuf[r0 + i] >> 16) & 255], 1);
    __syncthreads();

    int v = hcnt[t];
    int lane = t & 63, wv = t >> 6;
    int incl = v;
#pragma unroll
    for (int o = 1; o < 64; o <<= 1) {
        int u = __shfl_up(incl, o);
        if (lane >= o) incl += u;
    }
    if (lane == 63) wtot[wv] = incl;
    __syncthreads();
    if (t == 0) {
        int r = 0;
        for (int w = 0; w < 4; ++w) { int x = wtot[w]; wtot[w] = r; r += x; }
    }
    __syncthreads();
    int excl = incl - v + wtot[wv];

    int node = b * 256 + t;
    if (node < N_NODES) { cnt[node] = v; rofs[node] = r0 + excl; }
    if (node == N_NODES) rofs[N_NODES] = N_EDGES;
    cur2[t] = excl;
    __syncthreads();

    for (int i = t; i < m; i += 256) {
        unsigned int u = ebuf[r0 + i];
        int d8 = (u >> 16) & 255;
        int s = u & 0xFFFF;
        int slot = atomicAdd(&cur2[d8], 1);  // LDS atomic
        csr[r0 + slot] = (unsigned short)s;
    }
}

// ---------------------------------------------------------------------------
// O[n] = H[n] + sum_{s in csr[rofs[n]..rofs[n+1])} H[s].  Quarter-wave
// (16 lanes x ushort8 = 256B row); 4 independent gather chains per wave.
// ---------------------------------------------------------------------------
__global__ __launch_bounds__(256)
void k_agg(const bf16_t* __restrict__ H, const int* __restrict__ rofs,
           const unsigned short* __restrict__ csr, bf16_t* __restrict__ O,
           int n_rows) {
    int tid = threadIdx.x;
    int lane = tid & 15;
    int node = blockIdx.x * 16 + (tid >> 4);
    if (node >= n_rows) return;

    int r0 = rofs[node];
    int deg = rofs[node + 1] - r0;

    ushort8v u = ((const ushort8v*)(H + (size_t)node * F))[lane];
    float a0 = bf2f(u[0]), a1 = bf2f(u[1]), a2 = bf2f(u[2]), a3 = bf2f(u[3]);
    float a4 = bf2f(u[4]), a5 = bf2f(u[5]), a6 = bf2f(u[6]), a7 = bf2f(u[7]);

    const unsigned short* bk = csr + r0;
    int i = 0;
    for (; i + 4 <= deg; i += 4) {
        int s0 = bk[i + 0], s1 = bk[i + 1], s2 = bk[i + 2], s3 = bk[i + 3];
        ushort8v u0 = ((const ushort8v*)(H + (size_t)s0 * F))[lane];
        ushort8v u1 = ((const ushort8v*)(H + (size_t)s1 * F))[lane];
        ushort8v u2 = ((const ushort8v*)(H + (size_t)s2 * F))[lane];
        ushort8v u3 = ((const ushort8v*)(H + (size_t)s3 * F))[lane];
        a0 += bf2f(u0[0]) + bf2f(u1[0]) + bf2f(u2[0]) + bf2f(u3[0]);
        a1 += bf2f(u0[1]) + bf2f(u1[1]) + bf2f(u2[1]) + bf2f(u3[1]);
        a2 += bf2f(u0[2]) + bf2f(u1[2]) + bf2f(u2[2]) + bf2f(u3[2]);
        a3 += bf2f(u0[3]) + bf2f(u1[3]) + bf2f(u2[3]) + bf2f(u3[3]);
        a4 += bf2f(u0[4]) + bf2f(u1[4]) + bf2f(u2[4]) + bf2f(u3[4]);
        a5 += bf2f(u0[5]) + bf2f(u1[5]) + bf2f(u2[5]) + bf2f(u3[5]);
        a6 += bf2f(u0[6]) + bf2f(u1[6]) + bf2f(u2[6]) + bf2f(u3[6]);
        a7 += bf2f(u0[7]) + bf2f(u1[7]) + bf2f(u2[7]) + bf2f(u3[7]);
    }
    for (; i < deg; ++i) {
        ushort8v uv = ((const ushort8v*)(H + (size_t)bk[i] * F))[lane];
        a0 += bf2f(uv[0]); a1 += bf2f(uv[1]); a2 += bf2f(uv[2]); a3 += bf2f(uv[3]);
        a4 += bf2f(uv[4]); a5 += bf2f(uv[5]); a6 += bf2f(uv[6]); a7 += bf2f(uv[7]);
    }
    ushort8v o;
    o[0] = f2bf(a0); o[1] = f2bf(a1); o[2] = f2bf(a2); o[3] = f2bf(a3);
    o[4] = f2bf(a4); o[5] = f2bf(a5); o[6] = f2bf(a6); o[7] = f2bf(a7);
    ((ushort8v*)(O + (size_t)node * F))[lane] = o;
}

// ---------------------------------------------------------------------------
// out[n] = log_softmax( (S*H)[n] + sd_n*v1 + d_n*bc ), sd inline via cnt
// gathers; softmax reduced over the 16-lane group.
// ---------------------------------------------------------------------------
__global__ __launch_bounds__(256)
void k_agg_ep(const bf16_t* __restrict__ H, const int* __restrict__ rofs,
              const unsigned short* __restrict__ csr, const int* __restrict__ cnt,
              const float* __restrict__ v1, const float* __restrict__ bc,
              float* __restrict__ O, int n_rows) {
    int tid = threadIdx.x;
    int lane = tid & 15;
    int node = blockIdx.x * 16 + (tid >> 4);
    if (node >= n_rows) return;

    int r0 = rofs[node];
    int deg = rofs[node + 1] - r0;

    ushort8v u = ((const ushort8v*)(H + (size_t)node * F))[lane];
    float a0 = bf2f(u[0]), a1 = bf2f(u[1]), a2 = bf2f(u[2]), a3 = bf2f(u[3]);
    float a4 = bf2f(u[4]), a5 = bf2f(u[5]), a6 = bf2f(u[6]), a7 = bf2f(u[7]);

    const unsigned short* bk = csr + r0;

    int sdi = (lane == 0) ? (deg + 1) : 0;
    for (int j = lane; j < deg; j += 16) sdi += cnt[bk[j]] + 1;

    int i = 0;
    for (; i + 4 <= deg; i += 4) {
        int s0 = bk[i + 0], s1 = bk[i + 1], s2 = bk[i + 2], s3 = bk[i + 3];
        ushort8v u0 = ((const ushort8v*)(H + (size_t)s0 * F))[lane];
        ushort8v u1 = ((const ushort8v*)(H + (size_t)s1 * F))[lane];
        ushort8v u2 = ((const ushort8v*)(H + (size_t)s2 * F))[lane];
        ushort8v u3 = ((const ushort8v*)(H + (size_t)s3 * F))[lane];
        a0 += bf2f(u0[0]) + bf2f(u1[0]) + bf2f(u2[0]) + bf2f(u3[0]);
        a1 += bf2f(u0[1]) + bf2f(u1[1]) + bf2f(u2[1]) + bf2f(u3[1]);
        a2 += bf2f(u0[2]) + bf2f(u1[2]) + bf2f(u2[2]) + bf2f(u3[2]);
        a3 += bf2f(u0[3]) + bf2f(u1[3]) + bf2f(u2[3]) + bf2f(u3[3]);
        a4 += bf2f(u0[4]) + bf2f(u1[4]) + bf2f(u2[4]) + bf2f(u3[4]);
        a5 += bf2f(u0[5]) + bf2f(u1[5]) + bf2f(u2[5]) + bf2f(u3[5]);
        a6 += bf2f(u0[6]) + bf2f(u1[6]) + bf2f(u2[6]) + bf2f(u3[6]);
        a7 += bf2f(u0[7]) + bf2f(u1[7]) + bf2f(u2[7]) + bf2f(u3[7]);
    }
    for (; i < deg; ++i) {
        ushort8v uv = ((const ushort8v*)(H + (size_t)bk[i] * F))[lane];
        a0 += bf2f(uv[0]); a1 += bf2f(uv[1]); a2 += bf2f(uv[2]); a3 += bf2f(uv[3]);
        a4 += bf2f(uv[4]); a5 += bf2f(uv[5]); a6 += bf2f(uv[6]); a7 += bf2f(uv[7]);
    }

#pragma unroll
    for (int o = 8; o; o >>= 1) sdi += __shfl_xor(sdi, o);
    float sdn = (float)sdi;
    float dn = (float)(deg + 1);
    float4 v1a = ((const float4*)v1)[2 * lane], v1b = ((const float4*)v1)[2 * lane + 1];
    float4 bca = ((const float4*)bc)[2 * lane], bcb = ((const float4*)bc)[2 * lane + 1];
    a0 += sdn * v1a.x + dn * bca.x;
    a1 += sdn * v1a.y + dn * bca.y;
    a2 += sdn * v1a.z + dn * bca.z;
    a3 += sdn * v1a.w + dn * bca.w;
    a4 += sdn * v1b.x + dn * bcb.x;
    a5 += sdn * v1b.y + dn * bcb.y;
    a6 += sdn * v1b.z + dn * bcb.z;
    a7 += sdn * v1b.w + dn * bcb.w;

    float m = fmaxf(fmaxf(fmaxf(a0, a1), fmaxf(a2, a3)),
                    fmaxf(fmaxf(a4, a5), fmaxf(a6, a7)));
#pragma unroll
    for (int o = 8; o; o >>= 1) m = fmaxf(m, __shfl_xor(m, o));
    float s = expf(a0 - m) + expf(a1 - m) + expf(a2 - m) + expf(a3 - m)
            + expf(a4 - m) + expf(a5 - m) + expf(a6 - m) + expf(a7 - m);
#pragma unroll
    for (int o = 8; o; o >>= 1) s += __shfl_xor(s, o);
    float lse = m + logf(s);
    float4 oa, ob;
    oa.x = a0 - lse; oa.y = a1 - lse; oa.z = a2 - lse; oa.w = a3 - lse;
    ob.x = a4 - lse; ob.y = a5 - lse; ob.z = a6 - lse; ob.w = a7 - lse;
    ((float4*)(O + (size_t)node * F))[2 * lane] = oa;
    ((float4*)(O + (size_t)node * F))[2 * lane + 1] = ob;
}

extern "C" void kernel_launch(void* const* d_in, const int* in_sizes, int n_in,
                              void* d_out, int out_size, void* d_ws, size_t ws_size,
                              hipStream_t stream) {
    const float* x  = (const float*)d_in[0];
    const int* ei   = (const int*)d_in[1];
    const float* w1 = (const float*)d_in[2];
    const float* b1 = (const float*)d_in[3];
    const float* w2 = (const float*)d_in[4];
    const float* b2 = (const float*)d_in[5];
    float* out = (float*)d_out;

    const int* src = ei;
    const int* dst = ei + N_EDGES;

    // workspace layout (float offsets, 16B aligned)
    float* ws        = (float*)d_ws;
    float* Wc        = ws;                          // 16384
    float* bc        = ws + 16384;                  // 128
    float* v1        = ws + 16512;                  // 128
    bf16_t* Mbf      = (bf16_t*)(ws + 16640);       // 16384 bf16 (8192 f)
    int*   cnt       = (int*)(ws + 24832);          // 50048
    int*   rofs      = (int*)(ws + 74880);          // 50001 (pad 50048)
    int*   cnt2      = (int*)(ws + 124928);         // 12544 (pad 12800)
    int*   wofs2     = (int*)(ws + 137728);         // 12544 (pad 12800)
    int*   binofs    = (int*)(ws + 150528);         // 197 (pad 256)
    unsigned int* ebuf = (unsigned int*)(ws + 150784);     // 600000 u32
    unsigned short* csr = (unsigned short*)(ws + 750784);  // 600000 u16 (300000 f)
    bf16_t* g        = (bf16_t*)(ws + 1050784);     // 6.4M bf16 (3.2M f)
    bf16_t* a1       = (bf16_t*)(ws + 4250784);     // 6.4M bf16

    const int node_grid = (N_NODES + 15) / 16;  // 3125

    k_fuse<<<128, 128, 0, stream>>>(w1, b1, w2, b2, Wc, bc);
    // Mbf/v1 || passA coarse bin histogram
    k_fuse2h<<<128 + NHB, 256, 0, stream>>>(Wc, bc, Mbf, v1, dst, cnt2);
    // scan per-(bin,block) counts -> chunk bases + bin offsets
    k_binscan<<<1, 1024, 0, stream>>>(cnt2, wofs2, binofs);
    // g = x*M (MFMA) || passB LDS-sorted grouped scatter
    k_mainB<<<GEMM_BLOCKS + NHB, 256, 0, stream>>>(x, Mbf, g, src, dst,
                                                   cnt2, wofs2, ebuf);
    // per-bin: node histogram+scan -> cnt/rofs, scatter src into csr slice
    k_fine<<<NBINS, 256, 0, stream>>>(ebuf, binofs, cnt, rofs, csr);
    // a1 = S * g
    k_agg<<<node_grid, 256, 0, stream>>>(g, rofs, csr, a1, N_NODES);
    // out = log_softmax(S * a1 + sd*v1^T + d*bc^T)
    k_agg_ep<<<node_grid, 256, 0, stream>>>(a1, rofs, csr, cnt, v1, bc, out, N_NODES);
}

// Round 11
// 116.253 us; speedup vs baseline: 2.2742x; 1.0448x over previous
//
#include <hip/hip_runtime.h>
#include <hip/hip_bf16.h>

#define N_NODES 50000
#define N_EDGES 600000
#define F 128

#define GEMM_BLOCKS 782   // ceil(50000/64)
#define NBINS 196         // ceil(50000/256), bin = dst >> 8
#define NHB 64            // histogram/scatter blocks
#define EPB 9375          // edges per hist/scatter block (64*9375 == 600000)
#define BINCAP 4608       // max edges per bin (avg 3061, 18-sigma headroom)

typedef unsigned short bf16_t;
typedef __attribute__((ext_vector_type(8))) short short8v;
typedef __attribute__((ext_vector_type(8))) unsigned short ushort8v;
typedef __attribute__((ext_vector_type(4))) float f32x4;

__device__ inline float bf2f(bf16_t u) {
    union { unsigned int i; float f; } c;
    c.i = ((unsigned int)u) << 16;
    return c.f;
}
__device__ inline bf16_t f2bf(float f) {  // round-to-nearest-even
    union { float f; unsigned int i; } c;
    c.f = f;
    unsigned int lsb = (c.i >> 16) & 1;
    c.i += 0x7fffu + lsb;
    return (bf16_t)(c.i >> 16);
}

// ---------------------------------------------------------------------------
// K1: blocks [0,128) = weight fusion (Wc = w2@w1, bc = w2@b1+b2);
//     blocks [128,128+NHB) = passA coarse histogram of dst>>8 -> cnt2.
// The two roles are fully independent -> overlap on device.
// ---------------------------------------------------------------------------
__global__ __launch_bounds__(256)
void k_prep(const float* __restrict__ w1, const float* __restrict__ b1,
            const float* __restrict__ w2, const float* __restrict__ b2,
            float* __restrict__ Wc, float* __restrict__ bc,
            const int* __restrict__ dst, int* __restrict__ cnt2) {
    __shared__ int hist[NBINS];
    int bid = blockIdx.x;
    int tid = threadIdx.x;
    if (bid < 128) {
        int p = bid;
        if (tid < 128) {
            int j = tid;
            float s = 0.f;
            for (int o = 0; o < F; ++o) s = fmaf(w2[p * F + o], w1[o * F + j], s);
            Wc[p * F + j] = s;
            if (j == 0) {
                float t = b2[p];
                for (int o = 0; o < F; ++o) t = fmaf(w2[p * F + o], b1[o], t);
                bc[p] = t;
            }
        }
        return;
    }
    int hb = bid - 128;
    for (int b = tid; b < NBINS; b += 256) hist[b] = 0;
    __syncthreads();
    int e0 = hb * EPB;
    int e1 = min(e0 + EPB, N_EDGES);
    for (int e = e0 + tid; e < e1; e += 256) atomicAdd(&hist[dst[e] >> 8], 1);
    __syncthreads();
    for (int b = tid; b < NBINS; b += 256) cnt2[b * NHB + hb] = hist[b];
}

// ---------------------------------------------------------------------------
// K2 (1024 threads): blocks [0,16) = Mbf[p][k] = (W^T W^T)[k][p] in bf16
// (8 k-columns per block) + v1 = Wc*bc; block 16 = scan of cnt2 -> wofs2
// (per-(bin,block) chunk bases) + binofs (global bin starts). Independent.
// ---------------------------------------------------------------------------
__global__ __launch_bounds__(1024)
void k_prep2(const float* __restrict__ Wc, const float* __restrict__ bc,
             bf16_t* __restrict__ Mbf, float* __restrict__ v1,
             const int* __restrict__ cnt2, int* __restrict__ wofs2,
             int* __restrict__ binofs) {
    __shared__ int wtot[16];
    int bid = blockIdx.x;
    int t = threadIdx.x;

    if (bid < 16) {
        int kk = bid * 8 + (t >> 7);
        int p = t & 127;
        float s = 0.f;
        for (int o = 0; o < F; ++o) s = fmaf(Wc[p * F + o], Wc[o * F + kk], s);
        Mbf[p * F + kk] = f2bf(s);
        if (bid == 0 && t < 128) {
            float v = 0.f;
            for (int o = 0; o < F; ++o) v = fmaf(Wc[t * F + o], bc[o], v);
            v1[t] = v;
        }
        return;
    }

    // ---- binscan role ----
    const int NV = NBINS * NHB;  // 12544
    const int CH = 13;           // 1024*13 >= NV
    int lane = t & 63, wv = t >> 6;
    int base = t * CH;
    int s = 0;
    for (int i = 0; i < CH; ++i) {
        int idx = base + i;
        if (idx < NV) s += cnt2[idx];
    }
    int incl = s;
#pragma unroll
    for (int o = 1; o < 64; o <<= 1) {
        int u = __shfl_up(incl, o);
        if (lane >= o) incl += u;
    }
    if (lane == 63) wtot[wv] = incl;
    __syncthreads();
    if (t == 0) {
        int r = 0;
        for (int w = 0; w < 16; ++w) { int x = wtot[w]; wtot[w] = r; r += x; }
    }
    __syncthreads();
    int run = incl - s + wtot[wv];
    for (int i = 0; i < CH; ++i) {
        int idx = base + i;
        if (idx < NV) {
            int w = cnt2[idx];
            wofs2[idx] = run;
            if ((idx & (NHB - 1)) == 0) binofs[idx / NHB] = run;
            run += w;
        }
    }
    if (t == 0) binofs[NBINS] = N_EDGES;
}

// ---------------------------------------------------------------------------
// K3: blocks [0, GEMM_BLOCKS) = MFMA GEMM g = x*M; blocks [GEMM_BLOCKS,+NHB)
// = passB: LDS counting-sort of the block's edges by bin, then GROUPED flush
// into (bin,block) chunks of ebuf.
// ---------------------------------------------------------------------------
__global__ __launch_bounds__(256, 4)
void k_mainB(const float* __restrict__ X, const bf16_t* __restrict__ Mbf,
             bf16_t* __restrict__ G,
             const int* __restrict__ src, const int* __restrict__ dst,
             const int* __restrict__ cnt2, const int* __restrict__ wofs2,
             unsigned int* __restrict__ ebuf) {
    __shared__ __align__(16) unsigned char smem[EPB * 4 + 3 * NBINS * 4 + 16];
    const int bid = blockIdx.x;
    const int tid = threadIdx.x;

    if (bid >= GEMM_BLOCKS) {
        // ---- passB role ----
        unsigned int* pairs = (unsigned int*)smem;
        int* cur  = (int*)(smem + EPB * 4);
        int* lofs = cur + NBINS;
        int* gofs = lofs + NBINS;
        int* wt4  = gofs + NBINS;  // 4 ints
        int hb = bid - GEMM_BLOCKS;

        int c = 0;
        if (tid < NBINS) {
            c = cnt2[tid * NHB + hb];
            gofs[tid] = wofs2[tid * NHB + hb];
        }
        int lane = tid & 63, wv = tid >> 6;
        int incl = c;
#pragma unroll
        for (int o = 1; o < 64; o <<= 1) {
            int u = __shfl_up(incl, o);
            if (lane >= o) incl += u;
        }
        if (lane == 63) wt4[wv] = incl;
        __syncthreads();
        if (tid == 0) {
            int r = 0;
            for (int w = 0; w < 4; ++w) { int x = wt4[w]; wt4[w] = r; r += x; }
        }
        __syncthreads();
        if (tid < NBINS) {
            int e = incl - c + wt4[wv];
            lofs[tid] = e;
            cur[tid] = e;
        }
        __syncthreads();

        int e0 = hb * EPB;
        for (int e = e0 + tid; e < e0 + EPB; e += 256) {
            int d = dst[e];
            int s = src[e];
            unsigned int p = ((unsigned int)d << 16) | (unsigned int)s;
            int slot = atomicAdd(&cur[d >> 8], 1);  // LDS atomic
            pairs[slot] = p;
        }
        __syncthreads();

        for (int i = tid; i < EPB; i += 256) {
            unsigned int p = pairs[i];
            int b = p >> 24;
            ebuf[gofs[b] + (i - lofs[b])] = p;
        }
        return;
    }

    // ---- GEMM role ----
    unsigned short* Xs = (unsigned short*)smem;  // [64][128] bf16, swizzled
    const int row0 = bid * 64;

    for (int idx = tid; idx < 1024; idx += 256) {
        int r = idx >> 4, c = idx & 15;
        int grow = row0 + r;
        float4 va = {0.f, 0.f, 0.f, 0.f}, vb = {0.f, 0.f, 0.f, 0.f};
        if (grow < N_NODES) {
            const float4* xr = (const float4*)(X + (size_t)grow * F);
            va = xr[2 * c];
            vb = xr[2 * c + 1];
        }
        ushort8v u;
        u[0] = f2bf(va.x); u[1] = f2bf(va.y); u[2] = f2bf(va.z); u[3] = f2bf(va.w);
        u[4] = f2bf(vb.x); u[5] = f2bf(vb.y); u[6] = f2bf(vb.z); u[7] = f2bf(vb.w);
        *(ushort8v*)&Xs[r * 128 + (((c ^ (r & 7)) << 3))] = u;
    }
    __syncthreads();

    const int wid = tid >> 6;
    const int lane = tid & 63;
    const int wr = wid >> 1;
    const int wc = wid & 1;
    const int l15 = lane & 15;
    const int l4 = lane >> 4;
    const int sw = (l15 & 7);

    f32x4 acc[2][4] = {};

#pragma unroll
    for (int kc = 0; kc < 4; ++kc) {
        const int cS = ((kc * 4 + l4) ^ sw) << 3;
        short8v a0 = *(const short8v*)&Xs[(wr * 32 + 0 * 16 + l15) * 128 + cS];
        short8v a1 = *(const short8v*)&Xs[(wr * 32 + 1 * 16 + l15) * 128 + cS];
        const bf16_t* mb = Mbf + (size_t)(wc * 64 + l15) * F + kc * 32 + 8 * l4;
        short8v b0 = *(const short8v*)(mb + 0 * 16 * F);
        short8v b1 = *(const short8v*)(mb + 1 * 16 * F);
        short8v b2 = *(const short8v*)(mb + 2 * 16 * F);
        short8v b3 = *(const short8v*)(mb + 3 * 16 * F);
        acc[0][0] = __builtin_amdgcn_mfma_f32_16x16x32_bf16(a0, b0, acc[0][0], 0, 0, 0);
        acc[0][1] = __builtin_amdgcn_mfma_f32_16x16x32_bf16(a0, b1, acc[0][1], 0, 0, 0);
        acc[0][2] = __builtin_amdgcn_mfma_f32_16x16x32_bf16(a0, b2, acc[0][2], 0, 0, 0);
        acc[0][3] = __builtin_amdgcn_mfma_f32_16x16x32_bf16(a0, b3, acc[0][3], 0, 0, 0);
        acc[1][0] = __builtin_amdgcn_mfma_f32_16x16x32_bf16(a1, b0, acc[1][0], 0, 0, 0);
        acc[1][1] = __builtin_amdgcn_mfma_f32_16x16x32_bf16(a1, b1, acc[1][1], 0, 0, 0);
        acc[1][2] = __builtin_amdgcn_mfma_f32_16x16x32_bf16(a1, b2, acc[1][2], 0, 0, 0);
        acc[1][3] = __builtin_amdgcn_mfma_f32_16x16x32_bf16(a1, b3, acc[1][3], 0, 0, 0);
    }

#pragma unroll
    for (int mt = 0; mt < 2; ++mt) {
#pragma unroll
        for (int nt = 0; nt < 4; ++nt) {
#pragma unroll
            for (int r = 0; r < 4; ++r) {
                int grow = row0 + wr * 32 + mt * 16 + l4 * 4 + r;
                if (grow < N_NODES) {
                    int gcol = wc * 64 + nt * 16 + l15;
                    G[(size_t)grow * F + gcol] = f2bf(acc[mt][nt][r]);
                }
            }
        }
    }
}

// ---------------------------------------------------------------------------
// K4: per-bin finalize + FIRST AGGREGATION fused. One 1024-thread block per
// bin: load ebuf slice to LDS -> histogram + scan -> cnt/rofs, LDS counting
// sort -> ssrc (+ grouped csr write for agg_ep), then aggregate the bin's
// 256 nodes reading edge list from LDS: a1[n] = g[n] + sum g[ssrc].
// ---------------------------------------------------------------------------
__global__ __launch_bounds__(1024)
void k_fineagg(const unsigned int* __restrict__ ebuf, const int* __restrict__ binofs,
               const bf16_t* __restrict__ g,
               int* __restrict__ cnt, int* __restrict__ rofs,
               unsigned short* __restrict__ csr, bf16_t* __restrict__ a1) {
    __shared__ unsigned int pairs[BINCAP];
    __shared__ unsigned short ssrc[BINCAP];
    __shared__ int hcnt[256];
    __shared__ int hofs[256];
    __shared__ int cur[256];
    __shared__ int wtot[4];
    const int b = blockIdx.x;
    const int t = threadIdx.x;
    const int r0 = binofs[b];
    const int m = binofs[b + 1] - r0;

    for (int i = t; i < m; i += 1024) pairs[i] = ebuf[r0 + i];
    if (t < 256) hcnt[t] = 0;
    __syncthreads();
    for (int i = t; i < m; i += 1024) atomicAdd(&hcnt[(pairs[i] >> 16) & 255], 1);
    __syncthreads();

    int v = 0, incl = 0;
    int lane = t & 63, wv = t >> 6;
    if (t < 256) {
        v = hcnt[t];
        incl = v;
#pragma unroll
        for (int o = 1; o < 64; o <<= 1) {
            int u = __shfl_up(incl, o);
            if (lane >= o) incl += u;
        }
        if (lane == 63) wtot[wv] = incl;
    }
    __syncthreads();
    if (t == 0) {
        int r = 0;
        for (int w = 0; w < 4; ++w) { int x = wtot[w]; wtot[w] = r; r += x; }
    }
    __syncthreads();
    if (t < 256) {
        int excl = incl - v + wtot[wv];
        hofs[t] = excl;
        cur[t] = excl;
        int node = b * 256 + t;
        if (node < N_NODES) { cnt[node] = v; rofs[node] = r0 + excl; }
        else if (node == N_NODES) rofs[node] = N_EDGES;
    }
    __syncthreads();

    for (int i = t; i < m; i += 1024) {
        unsigned int u = pairs[i];
        int d8 = (u >> 16) & 255;
        int slot = atomicAdd(&cur[d8], 1);  // LDS atomic
        ssrc[slot] = (unsigned short)(u & 0xFFFF);
    }
    __syncthreads();
    for (int i = t; i < m; i += 1024) csr[r0 + i] = ssrc[i];

    // ---- aggregation for this bin's nodes (edge list in LDS) ----
    const int lane16 = t & 15;
    const int grp = t >> 4;  // 0..63
    for (int ln = grp; ln < 256; ln += 64) {
        int node = b * 256 + ln;
        if (node >= N_NODES) continue;
        int deg = hcnt[ln];
        int rl = hofs[ln];

        ushort8v u = ((const ushort8v*)(g + (size_t)node * F))[lane16];
        float a0 = bf2f(u[0]), a1_ = bf2f(u[1]), a2 = bf2f(u[2]), a3 = bf2f(u[3]);
        float a4 = bf2f(u[4]), a5 = bf2f(u[5]), a6 = bf2f(u[6]), a7 = bf2f(u[7]);

        int i = 0;
        for (; i + 4 <= deg; i += 4) {
            int s0 = ssrc[rl + i], s1 = ssrc[rl + i + 1];
            int s2 = ssrc[rl + i + 2], s3 = ssrc[rl + i + 3];
            ushort8v u0 = ((const ushort8v*)(g + (size_t)s0 * F))[lane16];
            ushort8v u1 = ((const ushort8v*)(g + (size_t)s1 * F))[lane16];
            ushort8v u2 = ((const ushort8v*)(g + (size_t)s2 * F))[lane16];
            ushort8v u3 = ((const ushort8v*)(g + (size_t)s3 * F))[lane16];
            a0 += bf2f(u0[0]) + bf2f(u1[0]) + bf2f(u2[0]) + bf2f(u3[0]);
            a1_ += bf2f(u0[1]) + bf2f(u1[1]) + bf2f(u2[1]) + bf2f(u3[1]);
            a2 += bf2f(u0[2]) + bf2f(u1[2]) + bf2f(u2[2]) + bf2f(u3[2]);
            a3 += bf2f(u0[3]) + bf2f(u1[3]) + bf2f(u2[3]) + bf2f(u3[3]);
            a4 += bf2f(u0[4]) + bf2f(u1[4]) + bf2f(u2[4]) + bf2f(u3[4]);
            a5 += bf2f(u0[5]) + bf2f(u1[5]) + bf2f(u2[5]) + bf2f(u3[5]);
            a6 += bf2f(u0[6]) + bf2f(u1[6]) + bf2f(u2[6]) + bf2f(u3[6]);
            a7 += bf2f(u0[7]) + bf2f(u1[7]) + bf2f(u2[7]) + bf2f(u3[7]);
        }
        for (; i < deg; ++i) {
            int s = ssrc[rl + i];
            ushort8v uv = ((const ushort8v*)(g + (size_t)s * F))[lane16];
            a0 += bf2f(uv[0]); a1_ += bf2f(uv[1]); a2 += bf2f(uv[2]); a3 += bf2f(uv[3]);
            a4 += bf2f(uv[4]); a5 += bf2f(uv[5]); a6 += bf2f(uv[6]); a7 += bf2f(uv[7]);
        }
        ushort8v o;
        o[0] = f2bf(a0); o[1] = f2bf(a1_); o[2] = f2bf(a2); o[3] = f2bf(a3);
        o[4] = f2bf(a4); o[5] = f2bf(a5); o[6] = f2bf(a6); o[7] = f2bf(a7);
        ((ushort8v*)(a1 + (size_t)node * F))[lane16] = o;
    }
}

// ---------------------------------------------------------------------------
// K5: out[n] = log_softmax( (S*a1)[n] + sd_n*v1 + d_n*bc ), sd inline via
// cnt gathers; softmax reduced over the 16-lane group.
// ---------------------------------------------------------------------------
__global__ __launch_bounds__(256)
void k_agg_ep(const bf16_t* __restrict__ H, const int* __restrict__ rofs,
              const unsigned short* __restrict__ csr, const int* __restrict__ cnt,
              const float* __restrict__ v1, const float* __restrict__ bc,
              float* __restrict__ O, int n_rows) {
    int tid = threadIdx.x;
    int lane = tid & 15;
    int node = blockIdx.x * 16 + (tid >> 4);
    if (node >= n_rows) return;

    int r0 = rofs[node];
    int deg = rofs[node + 1] - r0;

    ushort8v u = ((const ushort8v*)(H + (size_t)node * F))[lane];
    float a0 = bf2f(u[0]), a1 = bf2f(u[1]), a2 = bf2f(u[2]), a3 = bf2f(u[3]);
    float a4 = bf2f(u[4]), a5 = bf2f(u[5]), a6 = bf2f(u[6]), a7 = bf2f(u[7]);

    const unsigned short* bk = csr + r0;

    int sdi = (lane == 0) ? (deg + 1) : 0;
    for (int j = lane; j < deg; j += 16) sdi += cnt[bk[j]] + 1;

    int i = 0;
    for (; i + 4 <= deg; i += 4) {
        int s0 = bk[i + 0], s1 = bk[i + 1], s2 = bk[i + 2], s3 = bk[i + 3];
        ushort8v u0 = ((const ushort8v*)(H + (size_t)s0 * F))[lane];
        ushort8v u1 = ((const ushort8v*)(H + (size_t)s1 * F))[lane];
        ushort8v u2 = ((const ushort8v*)(H + (size_t)s2 * F))[lane];
        ushort8v u3 = ((const ushort8v*)(H + (size_t)s3 * F))[lane];
        a0 += bf2f(u0[0]) + bf2f(u1[0]) + bf2f(u2[0]) + bf2f(u3[0]);
        a1 += bf2f(u0[1]) + bf2f(u1[1]) + bf2f(u2[1]) + bf2f(u3[1]);
        a2 += bf2f(u0[2]) + bf2f(u1[2]) + bf2f(u2[2]) + bf2f(u3[2]);
        a3 += bf2f(u0[3]) + bf2f(u1[3]) + bf2f(u2[3]) + bf2f(u3[3]);
        a4 += bf2f(u0[4]) + bf2f(u1[4]) + bf2f(u2[4]) + bf2f(u3[4]);
        a5 += bf2f(u0[5]) + bf2f(u1[5]) + bf2f(u2[5]) + bf2f(u3[5]);
        a6 += bf2f(u0[6]) + bf2f(u1[6]) + bf2f(u2[6]) + bf2f(u3[6]);
        a7 += bf2f(u0[7]) + bf2f(u1[7]) + bf2f(u2[7]) + bf2f(u3[7]);
    }
    for (; i < deg; ++i) {
        ushort8v uv = ((const ushort8v*)(H + (size_t)bk[i] * F))[lane];
        a0 += bf2f(uv[0]); a1 += bf2f(uv[1]); a2 += bf2f(uv[2]); a3 += bf2f(uv[3]);
        a4 += bf2f(uv[4]); a5 += bf2f(uv[5]); a6 += bf2f(uv[6]); a7 += bf2f(uv[7]);
    }

#pragma unroll
    for (int o = 8; o; o >>= 1) sdi += __shfl_xor(sdi, o);
    float sdn = (float)sdi;
    float dn = (float)(deg + 1);
    float4 v1a = ((const float4*)v1)[2 * lane], v1b = ((const float4*)v1)[2 * lane + 1];
    float4 bca = ((const float4*)bc)[2 * lane], bcb = ((const float4*)bc)[2 * lane + 1];
    a0 += sdn * v1a.x + dn * bca.x;
    a1 += sdn * v1a.y + dn * bca.y;
    a2 += sdn * v1a.z + dn * bca.z;
    a3 += sdn * v1a.w + dn * bca.w;
    a4 += sdn * v1b.x + dn * bcb.x;
    a5 += sdn * v1b.y + dn * bcb.y;
    a6 += sdn * v1b.z + dn * bcb.z;
    a7 += sdn * v1b.w + dn * bcb.w;

    float m = fmaxf(fmaxf(fmaxf(a0, a1), fmaxf(a2, a3)),
                    fmaxf(fmaxf(a4, a5), fmaxf(a6, a7)));
#pragma unroll
    for (int o = 8; o; o >>= 1) m = fmaxf(m, __shfl_xor(m, o));
    float s = expf(a0 - m) + expf(a1 - m) + expf(a2 - m) + expf(a3 - m)
            + expf(a4 - m) + expf(a5 - m) + expf(a6 - m) + expf(a7 - m);
#pragma unroll
    for (int o = 8; o; o >>= 1) s += __shfl_xor(s, o);
    float lse = m + logf(s);
    float4 oa, ob;
    oa.x = a0 - lse; oa.y = a1 - lse; oa.z = a2 - lse; oa.w = a3 - lse;
    ob.x = a4 - lse; ob.y = a5 - lse; ob.z = a6 - lse; ob.w = a7 - lse;
    ((float4*)(O + (size_t)node * F))[2 * lane] = oa;
    ((float4*)(O + (size_t)node * F))[2 * lane + 1] = ob;
}

extern "C" void kernel_launch(void* const* d_in, const int* in_sizes, int n_in,
                              void* d_out, int out_size, void* d_ws, size_t ws_size,
                              hipStream_t stream) {
    const float* x  = (const float*)d_in[0];
    const int* ei   = (const int*)d_in[1];
    const float* w1 = (const float*)d_in[2];
    const float* b1 = (const float*)d_in[3];
    const float* w2 = (const float*)d_in[4];
    const float* b2 = (const float*)d_in[5];
    float* out = (float*)d_out;

    const int* src = ei;
    const int* dst = ei + N_EDGES;

    // workspace layout (float offsets, 16B aligned)
    float* ws        = (float*)d_ws;
    float* Wc        = ws;                          // 16384
    float* bc        = ws + 16384;                  // 128
    float* v1        = ws + 16512;                  // 128
    bf16_t* Mbf      = (bf16_t*)(ws + 16640);       // 16384 bf16 (8192 f)
    int*   cnt       = (int*)(ws + 24832);          // 50048
    int*   rofs      = (int*)(ws + 74880);          // 50001 (pad 50048)
    int*   cnt2      = (int*)(ws + 124928);         // 12544 (pad 12800)
    int*   wofs2     = (int*)(ws + 137728);         // 12544 (pad 12800)
    int*   binofs    = (int*)(ws + 150528);         // 197 (pad 256)
    unsigned int* ebuf = (unsigned int*)(ws + 150784);     // 600000 u32
    unsigned short* csr = (unsigned short*)(ws + 750784);  // 600000 u16 (300000 f)
    bf16_t* g        = (bf16_t*)(ws + 1050784);     // 6.4M bf16 (3.2M f)
    bf16_t* a1       = (bf16_t*)(ws + 4250784);     // 6.4M bf16

    const int node_grid = (N_NODES + 15) / 16;  // 3125

    // K1: weight fuse || coarse histogram
    k_prep<<<128 + NHB, 256, 0, stream>>>(w1, b1, w2, b2, Wc, bc, dst, cnt2);
    // K2: M + v1 || binscan
    k_prep2<<<17, 1024, 0, stream>>>(Wc, bc, Mbf, v1, cnt2, wofs2, binofs);
    // K3: g = x*M (MFMA) || passB LDS-sorted grouped scatter
    k_mainB<<<GEMM_BLOCKS + NHB, 256, 0, stream>>>(x, Mbf, g, src, dst,
                                                   cnt2, wofs2, ebuf);
    // K4: per-bin sort -> cnt/rofs/csr + first aggregation (a1 = S*g)
    k_fineagg<<<NBINS, 1024, 0, stream>>>(ebuf, binofs, g, cnt, rofs, csr, a1);
    // K5: out = log_softmax(S*a1 + sd*v1^T + d*bc^T)
    k_agg_ep<<<node_grid, 256, 0, stream>>>(a1, rofs, csr, cnt, v1, bc, out, N_NODES);
}